// Round 3
// baseline (2282.922 us; speedup 1.0000x reference)
//
#include <hip/hip_runtime.h>
#include <hip/hip_bf16.h>
#include <math.h>

typedef __hip_bfloat16 bf16;

#define BB 8
#define LL 2048
#define DD 512
#define FF 1025   // LL/2+1

__device__ __forceinline__ float b2f(bf16 v) { return __bfloat162float(v); }

// input loader: F32 selects fp32 vs bf16 interpretation of external tensors
template<bool F32>
__device__ __forceinline__ float ldin(const void* p, size_t i) {
    if (F32) return ((const float*)p)[i];
    else     return b2f(((const bf16*)p)[i]);
}

// ---------------------------------------------------------------------------
// dtype detector: counts sane bf16 exponent fields in first 4096 uint16 of x.
// bf16 data -> ~4096 sane; fp32 data viewed as uint16 -> ~2400. flag: 1=fp32.
// ---------------------------------------------------------------------------
__global__ __launch_bounds__(256) void detect_dtype(const unsigned short* __restrict__ x,
                                                    int* __restrict__ flag)
{
    __shared__ int cnt[256];
    int c = 0;
    for (int i = threadIdx.x; i < 4096; i += 256) {
        const int e = (x[i] >> 7) & 0xFF;
        c += (e >= 100 && e <= 150) ? 1 : 0;
    }
    cnt[threadIdx.x] = c;
    __syncthreads();
    for (int s = 128; s; s >>= 1) {
        if (threadIdx.x < s) cnt[threadIdx.x] += cnt[threadIdx.x + s];
        __syncthreads();
    }
    if (threadIdx.x == 0) *flag = (cnt[0] < 3400) ? 1 : 0;
}

// ---------------------------------------------------------------------------
// proj GEMM body: C(float)[M,512] = A[M,512] @ W[512,512] + b
// 64x64 tile, Kt=16, 256 threads, 4x4 per thread.
// ---------------------------------------------------------------------------
template<bool F32>
__device__ __forceinline__ void proj_body(const void* __restrict__ A,
                                          const void* __restrict__ W,
                                          const void* __restrict__ bias,
                                          float* __restrict__ C)
{
    __shared__ __align__(16) float As[16][68];   // [k][m]
    __shared__ __align__(16) float Bs[16][68];   // [k][n]
    const int tid = threadIdx.x;
    const int tx = tid & 15, ty = tid >> 4;
    const int m0 = blockIdx.x * 64, n0 = blockIdx.y * 64;

    const int ar  = tid >> 2,  ak0 = (tid & 3) * 4;   // A staging
    const int wk  = tid >> 4,  wc0 = (tid & 15) * 4;  // W staging

    float acc[4][4] = {};
    for (int kt = 0; kt < 512; kt += 16) {
        #pragma unroll
        for (int i = 0; i < 4; ++i)
            As[ak0 + i][ar] = ldin<F32>(A, (size_t)(m0 + ar) * 512 + kt + ak0 + i);
        #pragma unroll
        for (int j = 0; j < 4; ++j)
            Bs[wk][wc0 + j] = ldin<F32>(W, (size_t)(kt + wk) * 512 + n0 + wc0 + j);
        __syncthreads();
        #pragma unroll
        for (int kk = 0; kk < 16; ++kk) {
            const float4 a4 = *reinterpret_cast<const float4*>(&As[kk][ty * 4]);
            const float4 b4 = *reinterpret_cast<const float4*>(&Bs[kk][tx * 4]);
            const float av[4] = {a4.x, a4.y, a4.z, a4.w};
            const float bv[4] = {b4.x, b4.y, b4.z, b4.w};
            #pragma unroll
            for (int i = 0; i < 4; ++i)
                #pragma unroll
                for (int j = 0; j < 4; ++j)
                    acc[i][j] += av[i] * bv[j];
        }
        __syncthreads();
    }
    #pragma unroll
    for (int i = 0; i < 4; ++i) {
        float4 o;
        o.x = acc[i][0] + ldin<F32>(bias, n0 + tx * 4 + 0);
        o.y = acc[i][1] + ldin<F32>(bias, n0 + tx * 4 + 1);
        o.z = acc[i][2] + ldin<F32>(bias, n0 + tx * 4 + 2);
        o.w = acc[i][3] + ldin<F32>(bias, n0 + tx * 4 + 3);
        *reinterpret_cast<float4*>(&C[(size_t)(m0 + ty * 4 + i) * 512 + n0 + tx * 4]) = o;
    }
}

__global__ __launch_bounds__(256) void proj_gemm(
    const void* __restrict__ A,
    const void* __restrict__ W0, const void* __restrict__ b0, float* __restrict__ C0,
    const void* __restrict__ W1, const void* __restrict__ b1, float* __restrict__ C1,
    const void* __restrict__ W2, const void* __restrict__ b2, float* __restrict__ C2,
    const int* __restrict__ flag)
{
    const void* W; const void* bias; float* C;
    if (blockIdx.z == 0)      { W = W0; bias = b0; C = C0; }
    else if (blockIdx.z == 1) { W = W1; bias = b1; C = C1; }
    else                      { W = W2; bias = b2; C = C2; }
    if (*flag) proj_body<true >(A, W, bias, C);
    else       proj_body<false>(A, W, bias, C);
}

// ---------------------------------------------------------------------------
// out GEMM: out[M,512] = A(float)[M,512] @ W[512,512] + b
// output dtype follows input dtype flag: fp32 inputs -> fp32 out, else bf16.
// ---------------------------------------------------------------------------
template<bool F32>
__device__ __forceinline__ void out_body(const float* __restrict__ A,
                                         const void* __restrict__ W,
                                         const void* __restrict__ bias,
                                         void* __restrict__ Cv)
{
    __shared__ __align__(16) float As[16][68];
    __shared__ __align__(16) float Bs[16][68];
    const int tid = threadIdx.x;
    const int tx = tid & 15, ty = tid >> 4;
    const int m0 = blockIdx.x * 64, n0 = blockIdx.y * 64;

    const int ar = tid >> 2, ak0 = (tid & 3) * 4;
    const int wk = tid >> 4, wc0 = (tid & 15) * 4;

    float acc[4][4] = {};
    for (int kt = 0; kt < 512; kt += 16) {
        #pragma unroll
        for (int i = 0; i < 4; ++i)
            As[ak0 + i][ar] = A[(size_t)(m0 + ar) * 512 + kt + ak0 + i];
        #pragma unroll
        for (int j = 0; j < 4; ++j)
            Bs[wk][wc0 + j] = ldin<F32>(W, (size_t)(kt + wk) * 512 + n0 + wc0 + j);
        __syncthreads();
        #pragma unroll
        for (int kk = 0; kk < 16; ++kk) {
            const float4 a4 = *reinterpret_cast<const float4*>(&As[kk][ty * 4]);
            const float4 b4 = *reinterpret_cast<const float4*>(&Bs[kk][tx * 4]);
            const float av[4] = {a4.x, a4.y, a4.z, a4.w};
            const float bv[4] = {b4.x, b4.y, b4.z, b4.w};
            #pragma unroll
            for (int i = 0; i < 4; ++i)
                #pragma unroll
                for (int j = 0; j < 4; ++j)
                    acc[i][j] += av[i] * bv[j];
        }
        __syncthreads();
    }
    #pragma unroll
    for (int i = 0; i < 4; ++i) {
        const size_t row = (size_t)(m0 + ty * 4 + i) * 512 + n0 + tx * 4;
        if (F32) {
            float4 o;
            o.x = acc[i][0] + ldin<F32>(bias, n0 + tx * 4 + 0);
            o.y = acc[i][1] + ldin<F32>(bias, n0 + tx * 4 + 1);
            o.z = acc[i][2] + ldin<F32>(bias, n0 + tx * 4 + 2);
            o.w = acc[i][3] + ldin<F32>(bias, n0 + tx * 4 + 3);
            *reinterpret_cast<float4*>(&((float*)Cv)[row]) = o;
        } else {
            union { ushort4 u; bf16 h[4]; } pk;
            #pragma unroll
            for (int j = 0; j < 4; ++j)
                pk.h[j] = __float2bfloat16(acc[i][j] + ldin<F32>(bias, n0 + tx * 4 + j));
            *reinterpret_cast<ushort4*>(&((bf16*)Cv)[row]) = pk.u;
        }
    }
}

__global__ __launch_bounds__(256) void out_gemm(const float* __restrict__ A,
                                                const void* __restrict__ W,
                                                const void* __restrict__ bias,
                                                void* __restrict__ C,
                                                const int* __restrict__ flag)
{
    if (*flag) out_body<true >(A, W, bias, C);
    else       out_body<false>(A, W, bias, C);
}

// ---------------------------------------------------------------------------
// forward FFT (real input, length 2048) along L for 2 columns per block.
// Stockham radix-2 in LDS; writes bins 0..1024 as float2 to dst[b,f,d].
// ---------------------------------------------------------------------------
__global__ __launch_bounds__(256) void rfft_cols(const float* __restrict__ src,
                                                 float2* __restrict__ dst)
{
    const int b = blockIdx.y;
    const int d0 = blockIdx.x * 2;
    __shared__ __align__(16) float2 sh[2][2][2048];   // [pingpong][col][n] = 64 KB
    const int tid = threadIdx.x;

    for (int u = tid; u < 2 * 2048; u += 256) {
        const int c = u & 1, l = u >> 1;
        sh[0][c][l] = make_float2(src[(size_t)(b * 2048 + l) * 512 + d0 + c], 0.f);
    }
    __syncthreads();

    int cur = 0, nn = 2048, s = 1, ls = 0;
    while (nn > 1) {
        const int m = nn >> 1;
        const float theta = -6.283185307179586f / (float)nn;
        for (int u = tid; u < 2 * 1024; u += 256) {
            const int c = u >> 10;
            const int t = u & 1023;
            const int p = t >> ls;
            const int q = t & (s - 1);
            float wi, wr;
            __sincosf(theta * (float)p, &wi, &wr);
            const float2 a  = sh[cur][c][q + s * p];
            const float2 bb = sh[cur][c][q + s * (p + m)];
            const float dx = a.x - bb.x, dy = a.y - bb.y;
            sh[cur ^ 1][c][q + s * 2 * p]       = make_float2(a.x + bb.x, a.y + bb.y);
            sh[cur ^ 1][c][q + s * (2 * p + 1)] = make_float2(dx * wr - dy * wi, dx * wi + dy * wr);
        }
        __syncthreads();
        cur ^= 1; nn = m; s <<= 1; ++ls;
    }
    for (int u = tid; u < 2 * FF; u += 256) {
        const int c = u & 1, f = u >> 1;
        dst[(size_t)(b * FF + f) * 512 + d0 + c] = sh[cur][c][f];
    }
}

// ---------------------------------------------------------------------------
// inverse FFT: 1025 bins -> 2048 real samples (x2 columns per block).
// ---------------------------------------------------------------------------
__global__ __launch_bounds__(256) void irfft_cols(const float2* __restrict__ Cf,
                                                  float* __restrict__ Ct)
{
    const int b = blockIdx.y;
    const int d0 = blockIdx.x * 2;
    __shared__ __align__(16) float2 sh[2][2][2048];
    const int tid = threadIdx.x;

    for (int u = tid; u < 2 * FF; u += 256) {
        const int c = u & 1, f = u >> 1;
        const float2 v = Cf[(size_t)(b * FF + f) * 512 + d0 + c];
        sh[0][c][f] = v;
        if (f >= 1 && f <= 1023)
            sh[0][c][2048 - f] = make_float2(v.x, -v.y);
    }
    __syncthreads();

    int cur = 0, nn = 2048, s = 1, ls = 0;
    while (nn > 1) {
        const int m = nn >> 1;
        const float theta = 6.283185307179586f / (float)nn;   // inverse: +
        for (int u = tid; u < 2 * 1024; u += 256) {
            const int c = u >> 10;
            const int t = u & 1023;
            const int p = t >> ls;
            const int q = t & (s - 1);
            float wi, wr;
            __sincosf(theta * (float)p, &wi, &wr);
            const float2 a  = sh[cur][c][q + s * p];
            const float2 bb = sh[cur][c][q + s * (p + m)];
            const float dx = a.x - bb.x, dy = a.y - bb.y;
            sh[cur ^ 1][c][q + s * 2 * p]       = make_float2(a.x + bb.x, a.y + bb.y);
            sh[cur ^ 1][c][q + s * (2 * p + 1)] = make_float2(dx * wr - dy * wi, dx * wi + dy * wr);
        }
        __syncthreads();
        cur ^= 1; nn = m; s <<= 1; ++ls;
    }
    for (int u = tid; u < 2 * 2048; u += 256) {
        const int c = u & 1, l = u >> 1;
        Ct[(size_t)(b * 2048 + l) * 512 + d0 + c] = sh[cur][c][l].x * (1.0f / 2048.0f);
    }
}

// ---------------------------------------------------------------------------
// att[b,f,g] = scale * | sum_d Qf[b,f,d] * Kf[b,g,d] |   (complex, no conj)
// ---------------------------------------------------------------------------
#define ATT_SCALE 0.04419417382415922f   // 512^-0.5

__global__ __launch_bounds__(256) void att_gemm(const float2* __restrict__ Qf,
                                                const float2* __restrict__ Kf,
                                                float* __restrict__ att)
{
    const int b = blockIdx.z;
    const int f0 = blockIdx.x * 64, g0 = blockIdx.y * 64;
    __shared__ __align__(16) float2 Qs[16][66];   // [k][f]
    __shared__ __align__(16) float2 Ks[16][66];   // [k][g]
    const int tid = threadIdx.x;
    const int tx = tid & 15, ty = tid >> 4;
    const int r = tid >> 2, k0 = (tid & 3) * 4;

    float ar[4][4] = {}; float ai[4][4] = {};
    for (int kt = 0; kt < 512; kt += 16) {
        const int fr = f0 + r, gr = g0 + r;
        #pragma unroll
        for (int i = 0; i < 4; ++i) {
            Qs[k0 + i][r] = (fr < FF) ? Qf[(size_t)(b * FF + fr) * 512 + kt + k0 + i]
                                      : make_float2(0.f, 0.f);
            Ks[k0 + i][r] = (gr < FF) ? Kf[(size_t)(b * FF + gr) * 512 + kt + k0 + i]
                                      : make_float2(0.f, 0.f);
        }
        __syncthreads();
        #pragma unroll
        for (int kk = 0; kk < 16; ++kk) {
            float2 q[4], k[4];
            #pragma unroll
            for (int i = 0; i < 4; ++i) q[i] = Qs[kk][ty * 4 + i];
            #pragma unroll
            for (int j = 0; j < 4; ++j) k[j] = Ks[kk][tx * 4 + j];
            #pragma unroll
            for (int i = 0; i < 4; ++i)
                #pragma unroll
                for (int j = 0; j < 4; ++j) {
                    ar[i][j] += q[i].x * k[j].x - q[i].y * k[j].y;
                    ai[i][j] += q[i].x * k[j].y + q[i].y * k[j].x;
                }
        }
        __syncthreads();
    }
    #pragma unroll
    for (int i = 0; i < 4; ++i) {
        const int f = f0 + ty * 4 + i;
        if (f >= FF) continue;
        #pragma unroll
        for (int j = 0; j < 4; ++j) {
            const int g = g0 + tx * 4 + j;
            if (g < FF)
                att[(size_t)(b * FF + f) * FF + g] =
                    ATT_SCALE * sqrtf(ar[i][j] * ar[i][j] + ai[i][j] * ai[i][j]);
        }
    }
}

// ---------------------------------------------------------------------------
// row softmax over g (1025), in place. One block per (b,f) row.
// ---------------------------------------------------------------------------
__global__ __launch_bounds__(256) void softmax_rows(float* __restrict__ att)
{
    const int row = blockIdx.x;
    float* p = att + (size_t)row * FF;
    const int tid = threadIdx.x;
    const int lane = tid & 63, wid = tid >> 6;
    __shared__ float red[4];

    float m = -1e30f;
    for (int i = tid; i < FF; i += 256) m = fmaxf(m, p[i]);
    #pragma unroll
    for (int o = 32; o; o >>= 1) m = fmaxf(m, __shfl_down(m, o));
    if (lane == 0) red[wid] = m;
    __syncthreads();
    m = fmaxf(fmaxf(red[0], red[1]), fmaxf(red[2], red[3]));
    __syncthreads();

    float s = 0.f;
    for (int i = tid; i < FF; i += 256) { const float e = expf(p[i] - m); p[i] = e; s += e; }
    #pragma unroll
    for (int o = 32; o; o >>= 1) s += __shfl_down(s, o);
    if (lane == 0) red[wid] = s;
    __syncthreads();
    s = red[0] + red[1] + red[2] + red[3];
    const float inv = 1.f / s;
    for (int i = tid; i < FF; i += 256) p[i] *= inv;
}

// ---------------------------------------------------------------------------
// Cf[b,f,d] = sum_g att[b,f,g] * Vf[b,g,d]   (real x complex)
// ---------------------------------------------------------------------------
__global__ __launch_bounds__(256) void ctx_gemm(const float* __restrict__ att,
                                                const float2* __restrict__ Vf,
                                                float2* __restrict__ Cf)
{
    const int b = blockIdx.z;
    const int f0 = blockIdx.x * 64;
    const int d0 = blockIdx.y * 64;
    __shared__ __align__(16) float  As[16][68];   // [g][f]
    __shared__ __align__(16) float2 Bs[16][66];   // [g][d]
    const int tid = threadIdx.x;
    const int tx = tid & 15, ty = tid >> 4;
    const int r = tid >> 2, k0 = (tid & 3) * 4;
    const int vk = tid >> 4, vc0 = (tid & 15) * 4;

    float cr[4][4] = {}; float ci[4][4] = {};
    for (int kt = 0; kt < FF; kt += 16) {
        const int fr = f0 + r;
        #pragma unroll
        for (int i = 0; i < 4; ++i) {
            const int g = kt + k0 + i;
            As[k0 + i][r] = (fr < FF && g < FF) ? att[(size_t)(b * FF + fr) * FF + g] : 0.f;
        }
        {
            const int g = kt + vk;
            #pragma unroll
            for (int j = 0; j < 4; ++j)
                Bs[vk][vc0 + j] = (g < FF) ? Vf[(size_t)(b * FF + g) * 512 + d0 + vc0 + j]
                                           : make_float2(0.f, 0.f);
        }
        __syncthreads();
        #pragma unroll
        for (int kk = 0; kk < 16; ++kk) {
            const float4 a4 = *reinterpret_cast<const float4*>(&As[kk][ty * 4]);
            const float a[4] = {a4.x, a4.y, a4.z, a4.w};
            float2 v[4];
            #pragma unroll
            for (int j = 0; j < 4; ++j) v[j] = Bs[kk][tx * 4 + j];
            #pragma unroll
            for (int i = 0; i < 4; ++i)
                #pragma unroll
                for (int j = 0; j < 4; ++j) {
                    cr[i][j] += a[i] * v[j].x;
                    ci[i][j] += a[i] * v[j].y;
                }
        }
        __syncthreads();
    }
    #pragma unroll
    for (int i = 0; i < 4; ++i) {
        const int f = f0 + ty * 4 + i;
        if (f >= FF) continue;
        #pragma unroll
        for (int j = 0; j < 4; ++j)
            Cf[(size_t)(b * FF + f) * 512 + d0 + tx * 4 + j] = make_float2(cr[i][j], ci[i][j]);
    }
}

// ---------------------------------------------------------------------------
// launch — 4-slot time-shared workspace, total ~134.6 MB (+ flag word)
// ---------------------------------------------------------------------------
extern "C" void kernel_launch(void* const* d_in, const int* in_sizes, int n_in,
                              void* d_out, int out_size, void* d_ws, size_t ws_size,
                              hipStream_t stream)
{
    const void* x  = d_in[0];
    const void* Wq = d_in[1]; const void* bq = d_in[2];
    const void* Wk = d_in[3]; const void* bk = d_in[4];
    const void* Wv = d_in[5]; const void* bv = d_in[6];
    const void* Wo = d_in[7]; const void* bo = d_in[8];

    // slot = max(time fp32 33.55MB, freq cplx 33.59MB, attn 33.62MB), 256-aligned
    const size_t SLOT = 33652736;
    char* ws = (char*)d_ws;
    char* s0 = ws;               char* s1 = ws + SLOT;
    char* s2 = ws + 2 * SLOT;    char* s3 = ws + 3 * SLOT;
    int* flag = (int*)(ws + 4 * SLOT);

    float*  Qt = (float*)s0;  float* Kt = (float*)s1;  float* Vt = (float*)s2;
    float2* Qf = (float2*)s3;                 // after rfft Q, s0 free
    float2* Kf = (float2*)s0;                 // after rfft K, s1 free
    float2* Vf = (float2*)s1;                 // after rfft V, s2 free
    float*  attn = (float*)s2;                // att gemm; Qf,Kf dead after
    float2* Cf = (float2*)s0;                 // ctx; over dead Kf
    float*  Ct = (float*)s3;                  // irfft; over dead Qf

    // 0. input dtype detection (flag: 0=bf16, 1=fp32)
    detect_dtype<<<1, 256, 0, stream>>>((const unsigned short*)x, flag);
    // 1. projections (q,k,v) -> time-domain fp32
    proj_gemm<<<dim3(256, 8, 3), 256, 0, stream>>>(x, Wq, bq, Qt, Wk, bk, Kt, Wv, bv, Vt, flag);
    // 2. rfft along L
    rfft_cols<<<dim3(256, 8), 256, 0, stream>>>(Qt, Qf);
    rfft_cols<<<dim3(256, 8), 256, 0, stream>>>(Kt, Kf);
    rfft_cols<<<dim3(256, 8), 256, 0, stream>>>(Vt, Vf);
    // 3. complex QK^T -> scale*|.|
    att_gemm<<<dim3(17, 17, 8), 256, 0, stream>>>(Qf, Kf, attn);
    // 4. softmax over g
    softmax_rows<<<dim3(BB * FF), 256, 0, stream>>>(attn);
    // 5. context = attn @ V (real x complex)
    ctx_gemm<<<dim3(17, 8, 8), 256, 0, stream>>>(attn, Vf, Cf);
    // 6. irfft -> time domain
    irfft_cols<<<dim3(256, 8), 256, 0, stream>>>(Cf, Ct);
    // 7. output projection -> out (dtype follows input dtype)
    out_gemm<<<dim3(256, 8), 256, 0, stream>>>(Ct, Wo, bo, d_out, flag);
}

// Round 4
// 1222.727 us; speedup vs baseline: 1.8671x; 1.8671x over previous
//
#include <hip/hip_runtime.h>
#include <hip/hip_bf16.h>
#include <math.h>

typedef __hip_bfloat16 bf16;
typedef __attribute__((ext_vector_type(8))) short short8;
typedef __attribute__((ext_vector_type(4))) float f32x4;

#define BB 8
#define LL 2048
#define DD 512
#define FF 1025   // LL/2+1
#define GP 1056   // g padded to 33*32 for ctx K-chunks
#define ATT_SCALE 0.04419417382415922f   // 512^-0.5

__device__ __forceinline__ float b2f(bf16 v) { return __bfloat162float(v); }

#define MFMA16(a, b, c) __builtin_amdgcn_mfma_f32_16x16x32_bf16((a), (b), (c), 0, 0, 0)

// input loader: F32 selects fp32 vs bf16 interpretation of external tensors
template<bool F32>
__device__ __forceinline__ float ldin(const void* p, size_t i) {
    if (F32) return ((const float*)p)[i];
    else     return b2f(((const bf16*)p)[i]);
}

// ---------------------------------------------------------------------------
// dtype detector (flag: 1 = fp32 inputs, 0 = bf16). R2->R3 evidence: fp32.
// ---------------------------------------------------------------------------
__global__ __launch_bounds__(256) void detect_dtype(const unsigned short* __restrict__ x,
                                                    int* __restrict__ flag)
{
    __shared__ int cnt[256];
    int c = 0;
    for (int i = threadIdx.x; i < 4096; i += 256) {
        const int e = (x[i] >> 7) & 0xFF;
        c += (e >= 100 && e <= 150) ? 1 : 0;
    }
    cnt[threadIdx.x] = c;
    __syncthreads();
    for (int s = 128; s; s >>= 1) {
        if (threadIdx.x < s) cnt[threadIdx.x] += cnt[threadIdx.x + s];
        __syncthreads();
    }
    if (threadIdx.x == 0) *flag = (cnt[0] < 3400) ? 1 : 0;
}

// ---------------------------------------------------------------------------
// proj GEMM: C(float)[M,512] = A[M,512] @ W[512,512] + b  (fp32 vector)
// ---------------------------------------------------------------------------
template<bool F32>
__device__ __forceinline__ void proj_body(const void* __restrict__ A,
                                          const void* __restrict__ W,
                                          const void* __restrict__ bias,
                                          float* __restrict__ C)
{
    __shared__ __align__(16) float As[16][68];
    __shared__ __align__(16) float Bs[16][68];
    const int tid = threadIdx.x;
    const int tx = tid & 15, ty = tid >> 4;
    const int m0 = blockIdx.x * 64, n0 = blockIdx.y * 64;
    const int ar  = tid >> 2,  ak0 = (tid & 3) * 4;
    const int wk  = tid >> 4,  wc0 = (tid & 15) * 4;

    float acc[4][4] = {};
    for (int kt = 0; kt < 512; kt += 16) {
        #pragma unroll
        for (int i = 0; i < 4; ++i)
            As[ak0 + i][ar] = ldin<F32>(A, (size_t)(m0 + ar) * 512 + kt + ak0 + i);
        #pragma unroll
        for (int j = 0; j < 4; ++j)
            Bs[wk][wc0 + j] = ldin<F32>(W, (size_t)(kt + wk) * 512 + n0 + wc0 + j);
        __syncthreads();
        #pragma unroll
        for (int kk = 0; kk < 16; ++kk) {
            const float4 a4 = *reinterpret_cast<const float4*>(&As[kk][ty * 4]);
            const float4 b4 = *reinterpret_cast<const float4*>(&Bs[kk][tx * 4]);
            const float av[4] = {a4.x, a4.y, a4.z, a4.w};
            const float bv[4] = {b4.x, b4.y, b4.z, b4.w};
            #pragma unroll
            for (int i = 0; i < 4; ++i)
                #pragma unroll
                for (int j = 0; j < 4; ++j)
                    acc[i][j] += av[i] * bv[j];
        }
        __syncthreads();
    }
    #pragma unroll
    for (int i = 0; i < 4; ++i) {
        float4 o;
        o.x = acc[i][0] + ldin<F32>(bias, n0 + tx * 4 + 0);
        o.y = acc[i][1] + ldin<F32>(bias, n0 + tx * 4 + 1);
        o.z = acc[i][2] + ldin<F32>(bias, n0 + tx * 4 + 2);
        o.w = acc[i][3] + ldin<F32>(bias, n0 + tx * 4 + 3);
        *reinterpret_cast<float4*>(&C[(size_t)(m0 + ty * 4 + i) * 512 + n0 + tx * 4]) = o;
    }
}

__global__ __launch_bounds__(256) void proj_gemm(
    const void* __restrict__ A,
    const void* __restrict__ W0, const void* __restrict__ b0, float* __restrict__ C0,
    const void* __restrict__ W1, const void* __restrict__ b1, float* __restrict__ C1,
    const void* __restrict__ W2, const void* __restrict__ b2, float* __restrict__ C2,
    const int* __restrict__ flag)
{
    const void* W; const void* bias; float* C;
    if (blockIdx.z == 0)      { W = W0; bias = b0; C = C0; }
    else if (blockIdx.z == 1) { W = W1; bias = b1; C = C1; }
    else                      { W = W2; bias = b2; C = C2; }
    if (*flag) proj_body<true >(A, W, bias, C);
    else       proj_body<false>(A, W, bias, C);
}

// ---------------------------------------------------------------------------
// out GEMM: out[M,512] = A(float)[M,512] @ W[512,512] + b ; out dtype per flag
// ---------------------------------------------------------------------------
template<bool F32>
__device__ __forceinline__ void out_body(const float* __restrict__ A,
                                         const void* __restrict__ W,
                                         const void* __restrict__ bias,
                                         void* __restrict__ Cv)
{
    __shared__ __align__(16) float As[16][68];
    __shared__ __align__(16) float Bs[16][68];
    const int tid = threadIdx.x;
    const int tx = tid & 15, ty = tid >> 4;
    const int m0 = blockIdx.x * 64, n0 = blockIdx.y * 64;
    const int ar = tid >> 2, ak0 = (tid & 3) * 4;
    const int wk = tid >> 4, wc0 = (tid & 15) * 4;

    float acc[4][4] = {};
    for (int kt = 0; kt < 512; kt += 16) {
        #pragma unroll
        for (int i = 0; i < 4; ++i)
            As[ak0 + i][ar] = A[(size_t)(m0 + ar) * 512 + kt + ak0 + i];
        #pragma unroll
        for (int j = 0; j < 4; ++j)
            Bs[wk][wc0 + j] = ldin<F32>(W, (size_t)(kt + wk) * 512 + n0 + wc0 + j);
        __syncthreads();
        #pragma unroll
        for (int kk = 0; kk < 16; ++kk) {
            const float4 a4 = *reinterpret_cast<const float4*>(&As[kk][ty * 4]);
            const float4 b4 = *reinterpret_cast<const float4*>(&Bs[kk][tx * 4]);
            const float av[4] = {a4.x, a4.y, a4.z, a4.w};
            const float bv[4] = {b4.x, b4.y, b4.z, b4.w};
            #pragma unroll
            for (int i = 0; i < 4; ++i)
                #pragma unroll
                for (int j = 0; j < 4; ++j)
                    acc[i][j] += av[i] * bv[j];
        }
        __syncthreads();
    }
    #pragma unroll
    for (int i = 0; i < 4; ++i) {
        const size_t row = (size_t)(m0 + ty * 4 + i) * 512 + n0 + tx * 4;
        if (F32) {
            float4 o;
            o.x = acc[i][0] + ldin<F32>(bias, n0 + tx * 4 + 0);
            o.y = acc[i][1] + ldin<F32>(bias, n0 + tx * 4 + 1);
            o.z = acc[i][2] + ldin<F32>(bias, n0 + tx * 4 + 2);
            o.w = acc[i][3] + ldin<F32>(bias, n0 + tx * 4 + 3);
            *reinterpret_cast<float4*>(&((float*)Cv)[row]) = o;
        } else {
            union { ushort4 u; bf16 h[4]; } pk;
            #pragma unroll
            for (int j = 0; j < 4; ++j)
                pk.h[j] = __float2bfloat16(acc[i][j] + ldin<F32>(bias, n0 + tx * 4 + j));
            *reinterpret_cast<ushort4*>(&((bf16*)Cv)[row]) = pk.u;
        }
    }
}

__global__ __launch_bounds__(256) void out_gemm(const float* __restrict__ A,
                                                const void* __restrict__ W,
                                                const void* __restrict__ bias,
                                                void* __restrict__ C,
                                                const int* __restrict__ flag)
{
    if (*flag) out_body<true >(A, W, bias, C);
    else       out_body<false>(A, W, bias, C);
}

// ---------------------------------------------------------------------------
// forward FFT (real in, L=2048) along L, 2 columns/block. Stockham radix-2.
// ---------------------------------------------------------------------------
__global__ __launch_bounds__(256) void rfft_cols(const float* __restrict__ src,
                                                 float2* __restrict__ dst)
{
    const int b = blockIdx.y;
    const int d0 = blockIdx.x * 2;
    __shared__ __align__(16) float2 sh[2][2][2048];
    const int tid = threadIdx.x;

    for (int u = tid; u < 2 * 2048; u += 256) {
        const int c = u & 1, l = u >> 1;
        sh[0][c][l] = make_float2(src[(size_t)(b * 2048 + l) * 512 + d0 + c], 0.f);
    }
    __syncthreads();

    int cur = 0, nn = 2048, s = 1, ls = 0;
    while (nn > 1) {
        const int m = nn >> 1;
        const float theta = -6.283185307179586f / (float)nn;
        for (int u = tid; u < 2 * 1024; u += 256) {
            const int c = u >> 10;
            const int t = u & 1023;
            const int p = t >> ls;
            const int q = t & (s - 1);
            float wi, wr;
            __sincosf(theta * (float)p, &wi, &wr);
            const float2 a  = sh[cur][c][q + s * p];
            const float2 bb = sh[cur][c][q + s * (p + m)];
            const float dx = a.x - bb.x, dy = a.y - bb.y;
            sh[cur ^ 1][c][q + s * 2 * p]       = make_float2(a.x + bb.x, a.y + bb.y);
            sh[cur ^ 1][c][q + s * (2 * p + 1)] = make_float2(dx * wr - dy * wi, dx * wi + dy * wr);
        }
        __syncthreads();
        cur ^= 1; nn = m; s <<= 1; ++ls;
    }
    for (int u = tid; u < 2 * FF; u += 256) {
        const int c = u & 1, f = u >> 1;
        dst[(size_t)(b * FF + f) * 512 + d0 + c] = sh[cur][c][f];
    }
}

// ---------------------------------------------------------------------------
// inverse FFT: 1025 bins -> 2048 real, 2 columns/block.
// ---------------------------------------------------------------------------
__global__ __launch_bounds__(256) void irfft_cols(const float2* __restrict__ Cf,
                                                  float* __restrict__ Ct)
{
    const int b = blockIdx.y;
    const int d0 = blockIdx.x * 2;
    __shared__ __align__(16) float2 sh[2][2][2048];
    const int tid = threadIdx.x;

    for (int u = tid; u < 2 * FF; u += 256) {
        const int c = u & 1, f = u >> 1;
        const float2 v = Cf[(size_t)(b * FF + f) * 512 + d0 + c];
        sh[0][c][f] = v;
        if (f >= 1 && f <= 1023)
            sh[0][c][2048 - f] = make_float2(v.x, -v.y);
    }
    __syncthreads();

    int cur = 0, nn = 2048, s = 1, ls = 0;
    while (nn > 1) {
        const int m = nn >> 1;
        const float theta = 6.283185307179586f / (float)nn;
        for (int u = tid; u < 2 * 1024; u += 256) {
            const int c = u >> 10;
            const int t = u & 1023;
            const int p = t >> ls;
            const int q = t & (s - 1);
            float wi, wr;
            __sincosf(theta * (float)p, &wi, &wr);
            const float2 a  = sh[cur][c][q + s * p];
            const float2 bb = sh[cur][c][q + s * (p + m)];
            const float dx = a.x - bb.x, dy = a.y - bb.y;
            sh[cur ^ 1][c][q + s * 2 * p]       = make_float2(a.x + bb.x, a.y + bb.y);
            sh[cur ^ 1][c][q + s * (2 * p + 1)] = make_float2(dx * wr - dy * wi, dx * wi + dy * wr);
        }
        __syncthreads();
        cur ^= 1; nn = m; s <<= 1; ++ls;
    }
    for (int u = tid; u < 2 * 2048; u += 256) {
        const int c = u & 1, l = u >> 1;
        Ct[(size_t)(b * 2048 + l) * 512 + d0 + c] = sh[cur][c][l].x * (1.0f / 2048.0f);
    }
}

// ---------------------------------------------------------------------------
// split Q/K freq arrays into bf16 hi/lo planes: dst = h0 | l0 | h1 | l1,
// each [8][1025][512]. h=bf16(x), l=bf16(x-h) -> ~16-bit mantissa coverage.
// ---------------------------------------------------------------------------
__global__ __launch_bounds__(256) void split_qk(const float2* __restrict__ src,
                                                bf16* __restrict__ dst)
{
    const size_t SP = (size_t)BB * FF * DD;
    const size_t i = (size_t)blockIdx.x * 256 + threadIdx.x;
    if (i >= SP) return;
    const float2 v = src[i];
    const bf16 h0 = __float2bfloat16(v.x);
    const bf16 h1 = __float2bfloat16(v.y);
    dst[i]          = h0;
    dst[i + SP]     = __float2bfloat16(v.x - b2f(h0));
    dst[i + 2 * SP] = h1;
    dst[i + 3 * SP] = __float2bfloat16(v.y - b2f(h1));
}

// ---------------------------------------------------------------------------
// att_mfma: att[b,f,g] = scale*|Qf[b,f,:]·Kf[b,g,:]| via split-bf16 MFMA.
// P=QrKr R=QiKi S=QrKi T=QiKr (each: hh+hl+lh). ar=P-R, ai=S+T.
// Block 64f x 64g, 4 waves (2x2 of 32x32), K=512 in chunks of 32.
// ---------------------------------------------------------------------------
__global__ __launch_bounds__(256) void att_mfma(const bf16* __restrict__ Asp,
                                                const bf16* __restrict__ Bsp,
                                                float* __restrict__ att)
{
    const size_t SP = (size_t)BB * FF * DD;
    const int b = blockIdx.z;
    const int f0 = blockIdx.x * 64, g0 = blockIdx.y * 64;
    const int tid = threadIdx.x;
    const int wv = tid >> 6, lane = tid & 63;
    const int wf = (wv >> 1) * 32, wg = (wv & 1) * 32;

    __shared__ __align__(16) bf16 Al[4][64][40];   // stride 40: 80B rows, 16B-aligned
    __shared__ __align__(16) bf16 Bl[4][64][40];

    f32x4 P[2][2] = {}; f32x4 R[2][2] = {}; f32x4 S[2][2] = {}; f32x4 T[2][2] = {};

    const int srow = tid >> 2;        // 0..63
    const int sk   = (tid & 3) * 8;   // 0,8,16,24
    const int m  = lane & 15, kq = (lane >> 4) * 8;

    for (int kt = 0; kt < 512; kt += 32) {
        #pragma unroll
        for (int arr = 0; arr < 4; ++arr) {
            uint4 av = make_uint4(0, 0, 0, 0), bv = make_uint4(0, 0, 0, 0);
            if (f0 + srow < FF)
                av = *(const uint4*)&Asp[(size_t)arr * SP + ((size_t)(b * FF + f0 + srow)) * 512 + kt + sk];
            if (g0 + srow < FF)
                bv = *(const uint4*)&Bsp[(size_t)arr * SP + ((size_t)(b * FF + g0 + srow)) * 512 + kt + sk];
            *(uint4*)&Al[arr][srow][sk] = av;
            *(uint4*)&Bl[arr][srow][sk] = bv;
        }
        __syncthreads();

        short8 af[2][4], bfr[2][4];
        #pragma unroll
        for (int s = 0; s < 2; ++s)
            #pragma unroll
            for (int arr = 0; arr < 4; ++arr) {
                af[s][arr]  = *(const short8*)&Al[arr][wf + s * 16 + m][kq];
                bfr[s][arr] = *(const short8*)&Bl[arr][wg + s * 16 + m][kq];
            }
        #pragma unroll
        for (int i = 0; i < 2; ++i)
            #pragma unroll
            for (int j = 0; j < 2; ++j) {
                // arr: 0=re_hi 1=re_lo 2=im_hi 3=im_lo
                P[i][j] = MFMA16(af[i][0], bfr[j][0], P[i][j]);
                P[i][j] = MFMA16(af[i][0], bfr[j][1], P[i][j]);
                P[i][j] = MFMA16(af[i][1], bfr[j][0], P[i][j]);
                R[i][j] = MFMA16(af[i][2], bfr[j][2], R[i][j]);
                R[i][j] = MFMA16(af[i][2], bfr[j][3], R[i][j]);
                R[i][j] = MFMA16(af[i][3], bfr[j][2], R[i][j]);
                S[i][j] = MFMA16(af[i][0], bfr[j][2], S[i][j]);
                S[i][j] = MFMA16(af[i][0], bfr[j][3], S[i][j]);
                S[i][j] = MFMA16(af[i][1], bfr[j][2], S[i][j]);
                T[i][j] = MFMA16(af[i][2], bfr[j][0], T[i][j]);
                T[i][j] = MFMA16(af[i][2], bfr[j][1], T[i][j]);
                T[i][j] = MFMA16(af[i][3], bfr[j][0], T[i][j]);
            }
        __syncthreads();
    }

    // C/D layout (m89-verified): n = lane&15, m = (lane>>4)*4 + reg
    const int n = lane & 15, rq = (lane >> 4) * 4;
    #pragma unroll
    for (int i = 0; i < 2; ++i)
        #pragma unroll
        for (int j = 0; j < 2; ++j)
            #pragma unroll
            for (int r = 0; r < 4; ++r) {
                const int f = f0 + wf + i * 16 + rq + r;
                const int g = g0 + wg + j * 16 + n;
                if (f < FF && g < FF) {
                    const float ar = P[i][j][r] - R[i][j][r];
                    const float ai = S[i][j][r] + T[i][j][r];
                    att[((size_t)(b * FF + f)) * FF + g] = ATT_SCALE * sqrtf(ar * ar + ai * ai);
                }
            }
}

// ---------------------------------------------------------------------------
// softmax over g (1025) per (b,f) row; writes fp32 in place + bf16 copy
// (zero-padded to GP=1056) for the ctx MFMA.
// ---------------------------------------------------------------------------
__global__ __launch_bounds__(256) void softmax_rows(float* __restrict__ att,
                                                    bf16* __restrict__ att16)
{
    const int row = blockIdx.x;               // b*FF + f
    float* p = att + (size_t)row * FF;
    bf16* q = att16 + (size_t)row * GP;
    const int tid = threadIdx.x;
    const int lane = tid & 63, wid = tid >> 6;
    __shared__ float red[4];

    float m = -1e30f;
    for (int i = tid; i < FF; i += 256) m = fmaxf(m, p[i]);
    #pragma unroll
    for (int o = 32; o; o >>= 1) m = fmaxf(m, __shfl_down(m, o));
    if (lane == 0) red[wid] = m;
    __syncthreads();
    m = fmaxf(fmaxf(red[0], red[1]), fmaxf(red[2], red[3]));
    __syncthreads();

    float s = 0.f;
    for (int i = tid; i < FF; i += 256) { const float e = expf(p[i] - m); p[i] = e; s += e; }
    #pragma unroll
    for (int o = 32; o; o >>= 1) s += __shfl_down(s, o);
    if (lane == 0) red[wid] = s;
    __syncthreads();
    s = red[0] + red[1] + red[2] + red[3];
    const float inv = 1.f / s;
    for (int i = tid; i < GP; i += 256) {
        if (i < FF) {
            const float v = p[i] * inv;
            p[i] = v;
            q[i] = __float2bfloat16(v);
        } else {
            q[i] = __float2bfloat16(0.f);
        }
    }
}

// ---------------------------------------------------------------------------
// transpose V: Vf[b,g,d] (float2) -> Vct[b,n,g] bf16, n=d for re, 512+d for im.
// 32x32 tiles via LDS. g padded to GP (pad cols untouched; attn pad is zero).
// ---------------------------------------------------------------------------
__global__ __launch_bounds__(256) void transpose_v(const float2* __restrict__ Vf,
                                                   bf16* __restrict__ Vct)
{
    const int b = blockIdx.z;
    const int d0 = blockIdx.x * 32;
    const int g0 = blockIdx.y * 32;
    __shared__ float2 Tl[32][33];
    const int tid = threadIdx.x;

    for (int k = 0; k < 4; ++k) {
        const int idx = k * 256 + tid;
        const int lg = idx >> 5, ld = idx & 31;
        const int g = g0 + lg;
        Tl[lg][ld] = (g < FF) ? Vf[((size_t)(b * FF + g)) * 512 + d0 + ld]
                              : make_float2(0.f, 0.f);
    }
    __syncthreads();
    for (int k = 0; k < 4; ++k) {
        const int idx = k * 256 + tid;
        const int ld = idx >> 5, lg = idx & 31;
        const float2 v = Tl[lg][ld];
        Vct[((size_t)(b * 1024 + d0 + ld)) * GP + g0 + lg]       = __float2bfloat16(v.x);
        Vct[((size_t)(b * 1024 + 512 + d0 + ld)) * GP + g0 + lg] = __float2bfloat16(v.y);
    }
}

// ---------------------------------------------------------------------------
// ctx_mfma: Cf[b,f,d] = sum_g attn[b,f,g] * Vf[b,g,d]  (bf16 MFMA)
// A = att16[b,f,g(GP)], B = Vct[b,n,g(GP)] (n<512: re, else im). K=GP chunks 32.
// ---------------------------------------------------------------------------
__global__ __launch_bounds__(256) void ctx_mfma(const bf16* __restrict__ att16,
                                                const bf16* __restrict__ Vct,
                                                float* __restrict__ Cf)   // float2 viewed flat
{
    const int b = blockIdx.z;
    const int f0 = blockIdx.x * 64, n0 = blockIdx.y * 64;
    const int tid = threadIdx.x;
    const int wv = tid >> 6, lane = tid & 63;
    const int wf = (wv >> 1) * 32, wn = (wv & 1) * 32;

    __shared__ __align__(16) bf16 Al[64][40];
    __shared__ __align__(16) bf16 Bl[64][40];

    f32x4 acc[2][2] = {};
    const int srow = tid >> 2, sk = (tid & 3) * 8;
    const int m = lane & 15, kq = (lane >> 4) * 8;

    for (int kt = 0; kt < GP; kt += 32) {
        uint4 av = make_uint4(0, 0, 0, 0);
        if (f0 + srow < FF)
            av = *(const uint4*)&att16[((size_t)(b * FF + f0 + srow)) * GP + kt + sk];
        *(uint4*)&Al[srow][sk] = av;
        *(uint4*)&Bl[srow][sk] =
            *(const uint4*)&Vct[((size_t)(b * 1024 + n0 + srow)) * GP + kt + sk];
        __syncthreads();

        short8 af[2], bfr[2];
        #pragma unroll
        for (int s = 0; s < 2; ++s) {
            af[s]  = *(const short8*)&Al[wf + s * 16 + m][kq];
            bfr[s] = *(const short8*)&Bl[wn + s * 16 + m][kq];
        }
        #pragma unroll
        for (int i = 0; i < 2; ++i)
            #pragma unroll
            for (int j = 0; j < 2; ++j)
                acc[i][j] = MFMA16(af[i], bfr[j], acc[i][j]);
        __syncthreads();
    }

    const int nn = lane & 15, rq = (lane >> 4) * 4;
    #pragma unroll
    for (int i = 0; i < 2; ++i)
        #pragma unroll
        for (int j = 0; j < 2; ++j)
            #pragma unroll
            for (int r = 0; r < 4; ++r) {
                const int f = f0 + wf + i * 16 + rq + r;
                const int n = n0 + wn + j * 16 + nn;
                if (f < FF) {
                    const int d = n & 511, im = n >> 9;
                    Cf[(((size_t)(b * FF + f)) * 512 + d) * 2 + im] = acc[i][j][r];
                }
            }
}

// ---------------------------------------------------------------------------
// launch — 4-slot workspace (33.65MB each, proven footprint) + flag
// ---------------------------------------------------------------------------
extern "C" void kernel_launch(void* const* d_in, const int* in_sizes, int n_in,
                              void* d_out, int out_size, void* d_ws, size_t ws_size,
                              hipStream_t stream)
{
    const void* x  = d_in[0];
    const void* Wq = d_in[1]; const void* bq = d_in[2];
    const void* Wk = d_in[3]; const void* bk = d_in[4];
    const void* Wv = d_in[5]; const void* bv = d_in[6];
    const void* Wo = d_in[7]; const void* bo = d_in[8];

    const size_t SLOT = 33652736;
    char* ws = (char*)d_ws;
    char* s0 = ws;               char* s1 = ws + SLOT;
    char* s2 = ws + 2 * SLOT;    char* s3 = ws + 3 * SLOT;
    int* flag = (int*)(ws + 4 * SLOT);

    // lifetimes:
    float*  Qt   = (float*)s0;   float* Kt = (float*)s1;  float* Vt = (float*)s2;
    float2* Qf   = (float2*)s3;  // rfft Q: s0 dead after
    bf16*   Asp  = (bf16*)s0;    // split Q -> s0 (4 planes, 33.59MB); s3 dead after
    float2* Kf   = (float2*)s3;  // rfft K: s1 dead after
    bf16*   Bsp  = (bf16*)s1;    // split K -> s1; s3 dead after
    float*  attn = (float*)s3;   // att: 33.62MB
    float2* Vf   = (float2*)s1;  // rfft V (Bsp dead after att)
    bf16*   Vct  = (bf16*)s2;    // transpose (Vt dead): 17.3MB
    bf16*   att16= (bf16*)s0;    // softmax bf16 out (Asp dead): 17.3MB
    float2* Cf   = (float2*)s3;  // ctx out (attn fp32 dead after softmax)
    float*  Ct   = (float*)s0;   // irfft out (att16 dead after ctx)

    const int SPLIT_BLOCKS = (int)(((size_t)BB * FF * DD + 255) / 256);

    detect_dtype<<<1, 256, 0, stream>>>((const unsigned short*)x, flag);
    proj_gemm<<<dim3(256, 8, 3), 256, 0, stream>>>(x, Wq, bq, Qt, Wk, bk, Kt, Wv, bv, Vt, flag);
    rfft_cols<<<dim3(256, 8), 256, 0, stream>>>(Qt, Qf);
    split_qk<<<SPLIT_BLOCKS, 256, 0, stream>>>(Qf, Asp);
    rfft_cols<<<dim3(256, 8), 256, 0, stream>>>(Kt, Kf);
    split_qk<<<SPLIT_BLOCKS, 256, 0, stream>>>(Kf, Bsp);
    att_mfma<<<dim3(17, 17, 8), 256, 0, stream>>>(Asp, Bsp, attn);
    rfft_cols<<<dim3(256, 8), 256, 0, stream>>>(Vt, Vf);
    transpose_v<<<dim3(16, 33, 8), 256, 0, stream>>>(Vf, Vct);
    softmax_rows<<<dim3(BB * FF), 256, 0, stream>>>(attn, att16);
    ctx_mfma<<<dim3(17, 16, 8), 256, 0, stream>>>(att16, Vct, (float*)Cf);
    irfft_cols<<<dim3(256, 8), 256, 0, stream>>>(Cf, Ct);
    out_gemm<<<dim3(256, 8), 256, 0, stream>>>(Ct, Wo, bo, d_out, flag);
}

// Round 5
// 782.439 us; speedup vs baseline: 2.9177x; 1.5627x over previous
//
#include <hip/hip_runtime.h>
#include <hip/hip_bf16.h>
#include <math.h>

typedef __hip_bfloat16 bf16;
typedef __attribute__((ext_vector_type(8))) short short8;
typedef __attribute__((ext_vector_type(4))) float f32x4;

#define BB 8
#define LL 2048
#define DD 512
#define FF 1025   // LL/2+1
#define GP 1056   // g padded to 33*32 for ctx K-chunks
#define ATT_SCALE 0.04419417382415922f   // 512^-0.5

__device__ __forceinline__ float b2f(bf16 v) { return __bfloat162float(v); }
__device__ __forceinline__ bf16  f2b(float v) { return __float2bfloat16(v); }

#define MFMA16(a, b, c) __builtin_amdgcn_mfma_f32_16x16x32_bf16((a), (b), (c), 0, 0, 0)

template<bool F32>
__device__ __forceinline__ float ldin(const void* p, size_t i) {
    if (F32) return ((const float*)p)[i];
    else     return b2f(((const bf16*)p)[i]);
}

// ---------------------------------------------------------------------------
// dtype detector (flag: 1 = fp32 inputs, 0 = bf16). R2->R3 evidence: fp32.
// ---------------------------------------------------------------------------
__global__ __launch_bounds__(256) void detect_dtype(const unsigned short* __restrict__ x,
                                                    int* __restrict__ flag)
{
    __shared__ int cnt[256];
    int c = 0;
    for (int i = threadIdx.x; i < 4096; i += 256) {
        const int e = (x[i] >> 7) & 0xFF;
        c += (e >= 100 && e <= 150) ? 1 : 0;
    }
    cnt[threadIdx.x] = c;
    __syncthreads();
    for (int s = 128; s; s >>= 1) {
        if (threadIdx.x < s) cnt[threadIdx.x] += cnt[threadIdx.x + s];
        __syncthreads();
    }
    if (threadIdx.x == 0) *flag = (cnt[0] < 3400) ? 1 : 0;
}

// ---------------------------------------------------------------------------
// prep_bias: 4 bias vectors (512 each) -> fp32 contiguous [4][512]
// ---------------------------------------------------------------------------
__global__ __launch_bounds__(256) void prep_bias(const void* __restrict__ b0,
                                                 const void* __restrict__ b1,
                                                 const void* __restrict__ b2,
                                                 const void* __restrict__ b3,
                                                 float* __restrict__ bias_f,
                                                 const int* __restrict__ flag)
{
    const int idx = blockIdx.x * 256 + threadIdx.x;   // 0..2047
    const int which = idx >> 9, i = idx & 511;
    const void* src = which == 0 ? b0 : (which == 1 ? b1 : (which == 2 ? b2 : b3));
    bias_f[idx] = (*flag) ? ldin<true>(src, i) : ldin<false>(src, i);
}

// ---------------------------------------------------------------------------
// split_x: x[M,512] -> hi/lo bf16 planes (h = bf16(v), l = bf16(v-h))
// ---------------------------------------------------------------------------
__global__ __launch_bounds__(256) void split_x(const void* __restrict__ x,
                                               bf16* __restrict__ xh,
                                               bf16* __restrict__ xl,
                                               const int* __restrict__ flag)
{
    const size_t N = (size_t)BB * LL * DD;
    const size_t i = (size_t)blockIdx.x * 256 + threadIdx.x;
    if (i >= N) return;
    const float v = (*flag) ? ldin<true>(x, i) : ldin<false>(x, i);
    const bf16 h = f2b(v);
    xh[i] = h;
    xl[i] = f2b(v - b2f(h));
}

// ---------------------------------------------------------------------------
// split_w_t: W[512,512] -> transposed hi/lo bf16 planes WT[n][k].
// z selects Wq/Wk/Wv/Wo; planes at WT + z*524288 (hi), +262144 (lo).
// ---------------------------------------------------------------------------
__global__ __launch_bounds__(256) void split_w_t(const void* __restrict__ W0,
                                                 const void* __restrict__ W1,
                                                 const void* __restrict__ W2,
                                                 const void* __restrict__ W3,
                                                 bf16* __restrict__ WT,
                                                 const int* __restrict__ flag)
{
    const int z = blockIdx.z;
    const void* W = z == 0 ? W0 : (z == 1 ? W1 : (z == 2 ? W2 : W3));
    bf16* Wh = WT + (size_t)z * 524288;
    bf16* Wl = Wh + 262144;
    const int k0 = blockIdx.x * 32, n0 = blockIdx.y * 32;
    const bool f32 = (*flag) != 0;
    __shared__ float Tl[32][33];
    for (int it = 0; it < 4; ++it) {
        const int idx = it * 256 + threadIdx.x;
        const int lk = idx >> 5, ln = idx & 31;
        Tl[lk][ln] = f32 ? ldin<true>(W, (size_t)(k0 + lk) * 512 + n0 + ln)
                         : ldin<false>(W, (size_t)(k0 + lk) * 512 + n0 + ln);
    }
    __syncthreads();
    for (int it = 0; it < 4; ++it) {
        const int idx = it * 256 + threadIdx.x;
        const int ln = idx >> 5, lk = idx & 31;
        const float v = Tl[lk][ln];
        const bf16 h = f2b(v);
        Wh[(size_t)(n0 + ln) * 512 + k0 + lk] = h;
        Wl[(size_t)(n0 + ln) * 512 + k0 + lk] = f2b(v - b2f(h));
    }
}

// ---------------------------------------------------------------------------
// proj_mfma: C(fp32)[16384,512] = (xh+xl) @ (Wh+Wl) + bias. Split-bf16:
// hh + hl + lh MFMAs. 128x128 block, 4 waves (2x2 of 64x64), BK=32.
// ---------------------------------------------------------------------------
__global__ __launch_bounds__(256) void proj_mfma(const bf16* __restrict__ xh,
                                                 const bf16* __restrict__ xl,
                                                 const bf16* __restrict__ WT,
                                                 const float* __restrict__ bias_f,
                                                 float* __restrict__ C0,
                                                 float* __restrict__ C1,
                                                 float* __restrict__ C2)
{
    const int z = blockIdx.z;
    const bf16* Bh = WT + (size_t)z * 524288;
    const bf16* Blo = Bh + 262144;
    float* C = z == 0 ? C0 : (z == 1 ? C1 : C2);
    const float* bias = bias_f + z * 512;

    const int m0 = blockIdx.x * 128, n0 = blockIdx.y * 128;
    const int tid = threadIdx.x, wv = tid >> 6, lane = tid & 63;
    const int wm = (wv >> 1) * 64, wn = (wv & 1) * 64;

    __shared__ __align__(16) bf16 Al[2][128][40];
    __shared__ __align__(16) bf16 Bl[2][128][40];

    f32x4 acc[4][4] = {};
    const int srow = tid >> 2, sk = (tid & 3) * 8;
    const int mm = lane & 15, kq = (lane >> 4) * 8;

    for (int kt = 0; kt < 512; kt += 32) {
        #pragma unroll
        for (int p = 0; p < 2; ++p) {
            const int r = p * 64 + srow;
            *(uint4*)&Al[0][r][sk] = *(const uint4*)&xh[(size_t)(m0 + r) * 512 + kt + sk];
            *(uint4*)&Al[1][r][sk] = *(const uint4*)&xl[(size_t)(m0 + r) * 512 + kt + sk];
            *(uint4*)&Bl[0][r][sk] = *(const uint4*)&Bh[(size_t)(n0 + r) * 512 + kt + sk];
            *(uint4*)&Bl[1][r][sk] = *(const uint4*)&Blo[(size_t)(n0 + r) * 512 + kt + sk];
        }
        __syncthreads();

        short8 a_h[4], a_l[4], b_h[4], b_l[4];
        #pragma unroll
        for (int i = 0; i < 4; ++i) {
            a_h[i] = *(const short8*)&Al[0][wm + i * 16 + mm][kq];
            a_l[i] = *(const short8*)&Al[1][wm + i * 16 + mm][kq];
            b_h[i] = *(const short8*)&Bl[0][wn + i * 16 + mm][kq];
            b_l[i] = *(const short8*)&Bl[1][wn + i * 16 + mm][kq];
        }
        #pragma unroll
        for (int i = 0; i < 4; ++i)
            #pragma unroll
            for (int j = 0; j < 4; ++j) {
                acc[i][j] = MFMA16(a_h[i], b_h[j], acc[i][j]);
                acc[i][j] = MFMA16(a_h[i], b_l[j], acc[i][j]);
                acc[i][j] = MFMA16(a_l[i], b_h[j], acc[i][j]);
            }
        __syncthreads();
    }

    const int nn2 = lane & 15, rq = (lane >> 4) * 4;
    #pragma unroll
    for (int i = 0; i < 4; ++i)
        #pragma unroll
        for (int j = 0; j < 4; ++j) {
            const int col = n0 + wn + j * 16 + nn2;
            const float bv = bias[col];
            #pragma unroll
            for (int r = 0; r < 4; ++r) {
                const int row = m0 + wm + i * 16 + rq + r;
                C[(size_t)row * 512 + col] = acc[i][j][r] + bv;
            }
        }
}

// ---------------------------------------------------------------------------
// out_mfma: out[16384,512] = Ct16(bf16) @ WoT(hi plane) + bias. Plain bf16
// (last op: 0.4% rel is fine). 128x128 block. Out dtype per flag.
// ---------------------------------------------------------------------------
__global__ __launch_bounds__(256) void out_mfma(const bf16* __restrict__ A,
                                                const bf16* __restrict__ BhT,
                                                const float* __restrict__ bias,
                                                void* __restrict__ out,
                                                const int* __restrict__ flag)
{
    const int m0 = blockIdx.x * 128, n0 = blockIdx.y * 128;
    const int tid = threadIdx.x, wv = tid >> 6, lane = tid & 63;
    const int wm = (wv >> 1) * 64, wn = (wv & 1) * 64;

    __shared__ __align__(16) bf16 Al[128][40];
    __shared__ __align__(16) bf16 Bl[128][40];

    f32x4 acc[4][4] = {};
    const int srow = tid >> 2, sk = (tid & 3) * 8;
    const int mm = lane & 15, kq = (lane >> 4) * 8;

    for (int kt = 0; kt < 512; kt += 32) {
        #pragma unroll
        for (int p = 0; p < 2; ++p) {
            const int r = p * 64 + srow;
            *(uint4*)&Al[r][sk] = *(const uint4*)&A[(size_t)(m0 + r) * 512 + kt + sk];
            *(uint4*)&Bl[r][sk] = *(const uint4*)&BhT[(size_t)(n0 + r) * 512 + kt + sk];
        }
        __syncthreads();

        short8 af[4], bfr[4];
        #pragma unroll
        for (int i = 0; i < 4; ++i) {
            af[i]  = *(const short8*)&Al[wm + i * 16 + mm][kq];
            bfr[i] = *(const short8*)&Bl[wn + i * 16 + mm][kq];
        }
        #pragma unroll
        for (int i = 0; i < 4; ++i)
            #pragma unroll
            for (int j = 0; j < 4; ++j)
                acc[i][j] = MFMA16(af[i], bfr[j], acc[i][j]);
        __syncthreads();
    }

    const bool f32o = (*flag) != 0;
    const int nn2 = lane & 15, rq = (lane >> 4) * 4;
    #pragma unroll
    for (int i = 0; i < 4; ++i)
        #pragma unroll
        for (int j = 0; j < 4; ++j) {
            const int col = n0 + wn + j * 16 + nn2;
            const float bv = bias[col];
            #pragma unroll
            for (int r = 0; r < 4; ++r) {
                const int row = m0 + wm + i * 16 + rq + r;
                const float v = acc[i][j][r] + bv;
                if (f32o) ((float*)out)[(size_t)row * 512 + col] = v;
                else      ((bf16*)out)[(size_t)row * 512 + col] = f2b(v);
            }
        }
}

// ---------------------------------------------------------------------------
// rfft_cols: packed 2-real-columns-as-one-complex forward FFT (L=2048).
// LDS twiddle table; Stockham radix-2; unpack X1,X2 from Z and conj(Z[-f]).
// ---------------------------------------------------------------------------
__global__ __launch_bounds__(256) void rfft_cols(const float* __restrict__ src,
                                                 float2* __restrict__ dst)
{
    const int b = blockIdx.y;
    const int d0 = blockIdx.x * 2;
    __shared__ __align__(16) float2 sh[2][2048];   // 32 KB ping-pong
    __shared__ __align__(16) float2 tw[1024];      // 8 KB twiddles
    const int tid = threadIdx.x;

    for (int i = tid; i < 1024; i += 256) {
        float s, c;
        __sincosf(-6.283185307179586f * (float)i * (1.0f / 2048.0f), &s, &c);
        tw[i] = make_float2(c, s);
    }
    for (int l = tid; l < 2048; l += 256)
        sh[0][l] = make_float2(src[(size_t)(b * 2048 + l) * 512 + d0],
                               src[(size_t)(b * 2048 + l) * 512 + d0 + 1]);
    __syncthreads();

    int cur = 0, s = 1, ls = 0, tsh = 0;
    for (int nn = 2048; nn > 1; nn >>= 1) {
        const int m = nn >> 1;
        for (int t = tid; t < 1024; t += 256) {
            const int p = t >> ls;
            const int q = t & (s - 1);
            const float2 w  = tw[p << tsh];
            const float2 a  = sh[cur][q + s * p];
            const float2 bb = sh[cur][q + s * (p + m)];
            const float dx = a.x - bb.x, dy = a.y - bb.y;
            sh[cur ^ 1][q + s * 2 * p]       = make_float2(a.x + bb.x, a.y + bb.y);
            sh[cur ^ 1][q + s * (2 * p + 1)] = make_float2(dx * w.x - dy * w.y, dx * w.y + dy * w.x);
        }
        __syncthreads();
        cur ^= 1; s <<= 1; ++ls; ++tsh;
    }
    // unpack: X1 = (Z[f]+conj(Z[-f]))/2 ; X2 = -i(Z[f]-conj(Z[-f]))/2
    for (int f = tid; f < FF; f += 256) {
        const float2 Zf = sh[cur][f];
        const float2 Zc = sh[cur][(2048 - f) & 2047];
        const float2 X1 = make_float2(0.5f * (Zf.x + Zc.x), 0.5f * (Zf.y - Zc.y));
        const float wx = Zf.x - Zc.x, wy = Zf.y + Zc.y;
        const float2 X2 = make_float2(0.5f * wy, -0.5f * wx);
        dst[(size_t)(b * FF + f) * 512 + d0]     = X1;
        dst[(size_t)(b * FF + f) * 512 + d0 + 1] = X2;
    }
}

// ---------------------------------------------------------------------------
// irfft_cols: packed 2-column inverse (Z = Z1 + i*Z2, Hermitian-extended;
// DC/Nyquist imag zeroed = numpy c2r semantics). Writes bf16 time-domain.
// ---------------------------------------------------------------------------
__global__ __launch_bounds__(256) void irfft_cols(const float2* __restrict__ Cf,
                                                  bf16* __restrict__ Ct16)
{
    const int b = blockIdx.y;
    const int d0 = blockIdx.x * 2;
    __shared__ __align__(16) float2 sh[2][2048];
    __shared__ __align__(16) float2 tw[1024];
    const int tid = threadIdx.x;

    for (int i = tid; i < 1024; i += 256) {
        float s, c;
        __sincosf(-6.283185307179586f * (float)i * (1.0f / 2048.0f), &s, &c);
        tw[i] = make_float2(c, s);
    }
    for (int f = tid; f < FF; f += 256) {
        float2 c1 = Cf[(size_t)(b * FF + f) * 512 + d0];
        float2 c2 = Cf[(size_t)(b * FF + f) * 512 + d0 + 1];
        if (f == 0 || f == 1024) { c1.y = 0.f; c2.y = 0.f; }   // numpy ignores these
        // Z = Z1 + i*Z2 : (c1.x - c2.y, c1.y + c2.x)
        sh[0][f] = make_float2(c1.x - c2.y, c1.y + c2.x);
        if (f >= 1 && f <= 1023)
            // Z[2048-f] = conj(c1) + i*conj(c2) = (c1.x + c2.y, -c1.y + c2.x)
            sh[0][2048 - f] = make_float2(c1.x + c2.y, -c1.y + c2.x);
    }
    __syncthreads();

    int cur = 0, s = 1, ls = 0, tsh = 0;
    for (int nn = 2048; nn > 1; nn >>= 1) {
        const int m = nn >> 1;
        for (int t = tid; t < 1024; t += 256) {
            const int p = t >> ls;
            const int q = t & (s - 1);
            const float2 wv = tw[p << tsh];
            const float2 w = make_float2(wv.x, -wv.y);   // inverse: conjugate
            const float2 a  = sh[cur][q + s * p];
            const float2 bb = sh[cur][q + s * (p + m)];
            const float dx = a.x - bb.x, dy = a.y - bb.y;
            sh[cur ^ 1][q + s * 2 * p]       = make_float2(a.x + bb.x, a.y + bb.y);
            sh[cur ^ 1][q + s * (2 * p + 1)] = make_float2(dx * w.x - dy * w.y, dx * w.y + dy * w.x);
        }
        __syncthreads();
        cur ^= 1; s <<= 1; ++ls; ++tsh;
    }
    for (int l = tid; l < 2048; l += 256) {
        const float2 z = sh[cur][l];
        Ct16[(size_t)(b * 2048 + l) * 512 + d0]     = f2b(z.x * (1.0f / 2048.0f));
        Ct16[(size_t)(b * 2048 + l) * 512 + d0 + 1] = f2b(z.y * (1.0f / 2048.0f));
    }
}

// ---------------------------------------------------------------------------
// split_qk: freq float2 -> 4 bf16 planes (re_hi | re_lo | im_hi | im_lo)
// ---------------------------------------------------------------------------
__global__ __launch_bounds__(256) void split_qk(const float2* __restrict__ src,
                                                bf16* __restrict__ dst)
{
    const size_t SP = (size_t)BB * FF * DD;
    const size_t i = (size_t)blockIdx.x * 256 + threadIdx.x;
    if (i >= SP) return;
    const float2 v = src[i];
    const bf16 h0 = f2b(v.x);
    const bf16 h1 = f2b(v.y);
    dst[i]          = h0;
    dst[i + SP]     = f2b(v.x - b2f(h0));
    dst[i + 2 * SP] = h1;
    dst[i + 3 * SP] = f2b(v.y - b2f(h1));
}

// ---------------------------------------------------------------------------
// att_mfma: att[b,f,g] = scale*|Qf[b,f,:]·Kf[b,g,:]| via split-bf16 MFMA.
// P=QrKr R=QiKi S=QrKi T=QiKr (each hh+hl+lh). ar=P-R, ai=S+T.
// Block 64f x 64g, 4 waves (2x2 of 32x32), K=512 chunks of 32.
// ---------------------------------------------------------------------------
__global__ __launch_bounds__(256) void att_mfma(const bf16* __restrict__ Asp,
                                                const bf16* __restrict__ Bsp,
                                                float* __restrict__ att)
{
    const size_t SP = (size_t)BB * FF * DD;
    const int b = blockIdx.z;
    const int f0 = blockIdx.x * 64, g0 = blockIdx.y * 64;
    const int tid = threadIdx.x;
    const int wv = tid >> 6, lane = tid & 63;
    const int wf = (wv >> 1) * 32, wg = (wv & 1) * 32;

    __shared__ __align__(16) bf16 Al[4][64][40];
    __shared__ __align__(16) bf16 Bl[4][64][40];

    f32x4 P[2][2] = {}; f32x4 R[2][2] = {}; f32x4 S[2][2] = {}; f32x4 T[2][2] = {};

    const int srow = tid >> 2;
    const int sk   = (tid & 3) * 8;
    const int m  = lane & 15, kq = (lane >> 4) * 8;

    for (int kt = 0; kt < 512; kt += 32) {
        #pragma unroll
        for (int arr = 0; arr < 4; ++arr) {
            uint4 av = make_uint4(0, 0, 0, 0), bv = make_uint4(0, 0, 0, 0);
            if (f0 + srow < FF)
                av = *(const uint4*)&Asp[(size_t)arr * SP + ((size_t)(b * FF + f0 + srow)) * 512 + kt + sk];
            if (g0 + srow < FF)
                bv = *(const uint4*)&Bsp[(size_t)arr * SP + ((size_t)(b * FF + g0 + srow)) * 512 + kt + sk];
            *(uint4*)&Al[arr][srow][sk] = av;
            *(uint4*)&Bl[arr][srow][sk] = bv;
        }
        __syncthreads();

        short8 af[2][4], bfr[2][4];
        #pragma unroll
        for (int s = 0; s < 2; ++s)
            #pragma unroll
            for (int arr = 0; arr < 4; ++arr) {
                af[s][arr]  = *(const short8*)&Al[arr][wf + s * 16 + m][kq];
                bfr[s][arr] = *(const short8*)&Bl[arr][wg + s * 16 + m][kq];
            }
        #pragma unroll
        for (int i = 0; i < 2; ++i)
            #pragma unroll
            for (int j = 0; j < 2; ++j) {
                P[i][j] = MFMA16(af[i][0], bfr[j][0], P[i][j]);
                P[i][j] = MFMA16(af[i][0], bfr[j][1], P[i][j]);
                P[i][j] = MFMA16(af[i][1], bfr[j][0], P[i][j]);
                R[i][j] = MFMA16(af[i][2], bfr[j][2], R[i][j]);
                R[i][j] = MFMA16(af[i][2], bfr[j][3], R[i][j]);
                R[i][j] = MFMA16(af[i][3], bfr[j][2], R[i][j]);
                S[i][j] = MFMA16(af[i][0], bfr[j][2], S[i][j]);
                S[i][j] = MFMA16(af[i][0], bfr[j][3], S[i][j]);
                S[i][j] = MFMA16(af[i][1], bfr[j][2], S[i][j]);
                T[i][j] = MFMA16(af[i][2], bfr[j][0], T[i][j]);
                T[i][j] = MFMA16(af[i][2], bfr[j][1], T[i][j]);
                T[i][j] = MFMA16(af[i][3], bfr[j][0], T[i][j]);
            }
        __syncthreads();
    }

    const int n = lane & 15, rq = (lane >> 4) * 4;
    #pragma unroll
    for (int i = 0; i < 2; ++i)
        #pragma unroll
        for (int j = 0; j < 2; ++j)
            #pragma unroll
            for (int r = 0; r < 4; ++r) {
                const int f = f0 + wf + i * 16 + rq + r;
                const int g = g0 + wg + j * 16 + n;
                if (f < FF && g < FF) {
                    const float ar = P[i][j][r] - R[i][j][r];
                    const float ai = S[i][j][r] + T[i][j][r];
                    att[((size_t)(b * FF + f)) * FF + g] = ATT_SCALE * sqrtf(ar * ar + ai * ai);
                }
            }
}

// ---------------------------------------------------------------------------
// softmax over g per (b,f) row; fp32 in place + bf16 copy padded to GP.
// ---------------------------------------------------------------------------
__global__ __launch_bounds__(256) void softmax_rows(float* __restrict__ att,
                                                    bf16* __restrict__ att16)
{
    const int row = blockIdx.x;
    float* p = att + (size_t)row * FF;
    bf16* q = att16 + (size_t)row * GP;
    const int tid = threadIdx.x;
    const int lane = tid & 63, wid = tid >> 6;
    __shared__ float red[4];

    float m = -1e30f;
    for (int i = tid; i < FF; i += 256) m = fmaxf(m, p[i]);
    #pragma unroll
    for (int o = 32; o; o >>= 1) m = fmaxf(m, __shfl_down(m, o));
    if (lane == 0) red[wid] = m;
    __syncthreads();
    m = fmaxf(fmaxf(red[0], red[1]), fmaxf(red[2], red[3]));
    __syncthreads();

    float s = 0.f;
    for (int i = tid; i < FF; i += 256) { const float e = expf(p[i] - m); p[i] = e; s += e; }
    #pragma unroll
    for (int o = 32; o; o >>= 1) s += __shfl_down(s, o);
    if (lane == 0) red[wid] = s;
    __syncthreads();
    s = red[0] + red[1] + red[2] + red[3];
    const float inv = 1.f / s;
    for (int i = tid; i < GP; i += 256) {
        if (i < FF) {
            const float v = p[i] * inv;
            p[i] = v;
            q[i] = f2b(v);
        } else {
            q[i] = f2b(0.f);
        }
    }
}

// ---------------------------------------------------------------------------
// transpose V: Vf[b,g,d] float2 -> Vct[b,n,g] bf16 (n<512 re, else im).
// ---------------------------------------------------------------------------
__global__ __launch_bounds__(256) void transpose_v(const float2* __restrict__ Vf,
                                                   bf16* __restrict__ Vct)
{
    const int b = blockIdx.z;
    const int d0 = blockIdx.x * 32;
    const int g0 = blockIdx.y * 32;
    __shared__ float2 Tl[32][33];
    const int tid = threadIdx.x;

    for (int k = 0; k < 4; ++k) {
        const int idx = k * 256 + tid;
        const int lg = idx >> 5, ld = idx & 31;
        const int g = g0 + lg;
        Tl[lg][ld] = (g < FF) ? Vf[((size_t)(b * FF + g)) * 512 + d0 + ld]
                              : make_float2(0.f, 0.f);
    }
    __syncthreads();
    for (int k = 0; k < 4; ++k) {
        const int idx = k * 256 + tid;
        const int ld = idx >> 5, lg = idx & 31;
        const float2 v = Tl[lg][ld];
        Vct[((size_t)(b * 1024 + d0 + ld)) * GP + g0 + lg]       = f2b(v.x);
        Vct[((size_t)(b * 1024 + 512 + d0 + ld)) * GP + g0 + lg] = f2b(v.y);
    }
}

// ---------------------------------------------------------------------------
// ctx_mfma: Cf[b,f,d] = sum_g attn * Vf (bf16 MFMA, K=GP chunks of 32)
// ---------------------------------------------------------------------------
__global__ __launch_bounds__(256) void ctx_mfma(const bf16* __restrict__ att16,
                                                const bf16* __restrict__ Vct,
                                                float* __restrict__ Cf)
{
    const int b = blockIdx.z;
    const int f0 = blockIdx.x * 64, n0 = blockIdx.y * 64;
    const int tid = threadIdx.x;
    const int wv = tid >> 6, lane = tid & 63;
    const int wf = (wv >> 1) * 32, wn = (wv & 1) * 32;

    __shared__ __align__(16) bf16 Al[64][40];
    __shared__ __align__(16) bf16 Bl[64][40];

    f32x4 acc[2][2] = {};
    const int srow = tid >> 2, sk = (tid & 3) * 8;
    const int m = lane & 15, kq = (lane >> 4) * 8;

    for (int kt = 0; kt < GP; kt += 32) {
        uint4 av = make_uint4(0, 0, 0, 0);
        if (f0 + srow < FF)
            av = *(const uint4*)&att16[((size_t)(b * FF + f0 + srow)) * GP + kt + sk];
        *(uint4*)&Al[srow][sk] = av;
        *(uint4*)&Bl[srow][sk] =
            *(const uint4*)&Vct[((size_t)(b * 1024 + n0 + srow)) * GP + kt + sk];
        __syncthreads();

        short8 af[2], bfr[2];
        #pragma unroll
        for (int s = 0; s < 2; ++s) {
            af[s]  = *(const short8*)&Al[wf + s * 16 + m][kq];
            bfr[s] = *(const short8*)&Bl[wn + s * 16 + m][kq];
        }
        #pragma unroll
        for (int i = 0; i < 2; ++i)
            #pragma unroll
            for (int j = 0; j < 2; ++j)
                acc[i][j] = MFMA16(af[i], bfr[j], acc[i][j]);
        __syncthreads();
    }

    const int nn = lane & 15, rq = (lane >> 4) * 4;
    #pragma unroll
    for (int i = 0; i < 2; ++i)
        #pragma unroll
        for (int j = 0; j < 2; ++j)
            #pragma unroll
            for (int r = 0; r < 4; ++r) {
                const int f = f0 + wf + i * 16 + rq + r;
                const int n = n0 + wn + j * 16 + nn;
                if (f < FF) {
                    const int d = n & 511, im = n >> 9;
                    Cf[(((size_t)(b * FF + f)) * 512 + d) * 2 + im] = acc[i][j][r];
                }
            }
}

// ---------------------------------------------------------------------------
// launch — 4x33.65MB slots + 4MB weight region + bias + flag (~138.8 MB)
// ---------------------------------------------------------------------------
extern "C" void kernel_launch(void* const* d_in, const int* in_sizes, int n_in,
                              void* d_out, int out_size, void* d_ws, size_t ws_size,
                              hipStream_t stream)
{
    const void* x  = d_in[0];
    const void* Wq = d_in[1]; const void* bq = d_in[2];
    const void* Wk = d_in[3]; const void* bk = d_in[4];
    const void* Wv = d_in[5]; const void* bv = d_in[6];
    const void* Wo = d_in[7]; const void* bo = d_in[8];

    const size_t SLOT = 33652736;
    char* ws = (char*)d_ws;
    char* s0 = ws;               char* s1 = ws + SLOT;
    char* s2 = ws + 2 * SLOT;    char* s3 = ws + 3 * SLOT;
    char* wreg = ws + 4 * SLOT;                 // 8 bf16 planes: 4 MB
    bf16*  WT     = (bf16*)wreg;
    float* bias_f = (float*)(wreg + 4194304);   // 4*512 fp32
    int*   flag   = (int*)(wreg + 4194304 + 8192);

    // lifetimes (slot -> content over time):
    bf16*   xh   = (bf16*)s3;                   // split x
    bf16*   xl   = (bf16*)(s3 + 16777216);
    float*  Qt   = (float*)s0;  float* Kt = (float*)s1;  float* Vt = (float*)s2;
    float2* Qf   = (float2*)s3;                 // xh/xl dead after proj
    bf16*   Asp  = (bf16*)s0;                   // Qt dead after rfft Q
    float2* Kf   = (float2*)s3;                 // Qf dead after split
    bf16*   Bsp  = (bf16*)s1;                   // Kt dead
    float2* Vf   = (float2*)s3;                 // Kf dead
    bf16*   Vct  = (bf16*)s2;                   // Vt dead after rfft V
    float*  attn = (float*)s3;                  // Vf dead after transpose
    bf16*   att16= (bf16*)s0;                   // Asp dead after att
    float2* Cf   = (float2*)s1;                 // Bsp dead after att
    bf16*   Ct16 = (bf16*)s2;                   // Vct dead after ctx

    const int SPLITQ_BLOCKS = (int)(((size_t)BB * FF * DD + 255) / 256);
    const int SPLITX_BLOCKS = (int)(((size_t)BB * LL * DD + 255) / 256);

    detect_dtype<<<1, 256, 0, stream>>>((const unsigned short*)x, flag);
    prep_bias<<<8, 256, 0, stream>>>(bq, bk, bv, bo, bias_f, flag);
    split_x<<<SPLITX_BLOCKS, 256, 0, stream>>>(x, xh, xl, flag);
    split_w_t<<<dim3(16, 16, 4), 256, 0, stream>>>(Wq, Wk, Wv, Wo, WT, flag);
    proj_mfma<<<dim3(128, 4, 3), 256, 0, stream>>>(xh, xl, WT, bias_f, Qt, Kt, Vt);
    rfft_cols<<<dim3(256, 8), 256, 0, stream>>>(Qt, Qf);
    split_qk<<<SPLITQ_BLOCKS, 256, 0, stream>>>(Qf, Asp);
    rfft_cols<<<dim3(256, 8), 256, 0, stream>>>(Kt, Kf);
    split_qk<<<SPLITQ_BLOCKS, 256, 0, stream>>>(Kf, Bsp);
    rfft_cols<<<dim3(256, 8), 256, 0, stream>>>(Vt, Vf);
    transpose_v<<<dim3(16, 33, 8), 256, 0, stream>>>(Vf, Vct);
    att_mfma<<<dim3(17, 17, 8), 256, 0, stream>>>(Asp, Bsp, attn);
    softmax_rows<<<dim3(BB * FF), 256, 0, stream>>>(attn, att16);
    ctx_mfma<<<dim3(17, 16, 8), 256, 0, stream>>>(att16, Vct, (float*)Cf);
    irfft_cols<<<dim3(256, 8), 256, 0, stream>>>(Cf, Ct16);
    out_mfma<<<dim3(128, 4), 256, 0, stream>>>(Ct16, WT + 3 * 524288, bias_f + 3 * 512,
                                               d_out, flag);
}

// Round 6
// 780.534 us; speedup vs baseline: 2.9248x; 1.0024x over previous
//
#include <hip/hip_runtime.h>
#include <hip/hip_bf16.h>
#include <math.h>

typedef __hip_bfloat16 bf16;
typedef __attribute__((ext_vector_type(8))) short short8;
typedef __attribute__((ext_vector_type(4))) float f32x4;

#define BB 8
#define LL 2048
#define DD 512
#define FF 1025   // LL/2+1
#define GP 1056   // g padded to 33*32 for ctx K-chunks
#define ATT_SCALE 0.04419417382415922f   // 512^-0.5

__device__ __forceinline__ float b2f(bf16 v) { return __bfloat162float(v); }
__device__ __forceinline__ bf16  f2b(float v) { return __float2bfloat16(v); }

#define MFMA16(a, b, c) __builtin_amdgcn_mfma_f32_16x16x32_bf16((a), (b), (c), 0, 0, 0)

// exact bf16 negation of an 8-element fragment (sign-bit flip)
__device__ __forceinline__ short8 neg8(short8 v) {
    short8 r;
    #pragma unroll
    for (int t = 0; t < 8; ++t) r[t] = (short)(v[t] ^ (short)0x8000);
    return r;
}

template<bool F32>
__device__ __forceinline__ float ldin(const void* p, size_t i) {
    if (F32) return ((const float*)p)[i];
    else     return b2f(((const bf16*)p)[i]);
}

// ---------------------------------------------------------------------------
// dtype detector (flag: 1 = fp32 inputs, 0 = bf16). R2->R3 evidence: fp32.
// ---------------------------------------------------------------------------
__global__ __launch_bounds__(256) void detect_dtype(const unsigned short* __restrict__ x,
                                                    int* __restrict__ flag)
{
    __shared__ int cnt[256];
    int c = 0;
    for (int i = threadIdx.x; i < 4096; i += 256) {
        const int e = (x[i] >> 7) & 0xFF;
        c += (e >= 100 && e <= 150) ? 1 : 0;
    }
    cnt[threadIdx.x] = c;
    __syncthreads();
    for (int s = 128; s; s >>= 1) {
        if (threadIdx.x < s) cnt[threadIdx.x] += cnt[threadIdx.x + s];
        __syncthreads();
    }
    if (threadIdx.x == 0) *flag = (cnt[0] < 3400) ? 1 : 0;
}

// ---------------------------------------------------------------------------
// prep_bias: 4 bias vectors (512 each) -> fp32 contiguous [4][512]
// ---------------------------------------------------------------------------
__global__ __launch_bounds__(256) void prep_bias(const void* __restrict__ b0,
                                                 const void* __restrict__ b1,
                                                 const void* __restrict__ b2,
                                                 const void* __restrict__ b3,
                                                 float* __restrict__ bias_f,
                                                 const int* __restrict__ flag)
{
    const int idx = blockIdx.x * 256 + threadIdx.x;   // 0..2047
    const int which = idx >> 9, i = idx & 511;
    const void* src = which == 0 ? b0 : (which == 1 ? b1 : (which == 2 ? b2 : b3));
    bias_f[idx] = (*flag) ? ldin<true>(src, i) : ldin<false>(src, i);
}

// ---------------------------------------------------------------------------
// split_x: x[M,512] -> hi/lo bf16 planes (h = bf16(v), l = bf16(v-h))
// ---------------------------------------------------------------------------
__global__ __launch_bounds__(256) void split_x(const void* __restrict__ x,
                                               bf16* __restrict__ xh,
                                               bf16* __restrict__ xl,
                                               const int* __restrict__ flag)
{
    const size_t N = (size_t)BB * LL * DD;
    const size_t i = (size_t)blockIdx.x * 256 + threadIdx.x;
    if (i >= N) return;
    const float v = (*flag) ? ldin<true>(x, i) : ldin<false>(x, i);
    const bf16 h = f2b(v);
    xh[i] = h;
    xl[i] = f2b(v - b2f(h));
}

// ---------------------------------------------------------------------------
// split_w_t: W[512,512] -> transposed hi/lo bf16 planes WT[n][k].
// ---------------------------------------------------------------------------
__global__ __launch_bounds__(256) void split_w_t(const void* __restrict__ W0,
                                                 const void* __restrict__ W1,
                                                 const void* __restrict__ W2,
                                                 const void* __restrict__ W3,
                                                 bf16* __restrict__ WT,
                                                 const int* __restrict__ flag)
{
    const int z = blockIdx.z;
    const void* W = z == 0 ? W0 : (z == 1 ? W1 : (z == 2 ? W2 : W3));
    bf16* Wh = WT + (size_t)z * 524288;
    bf16* Wl = Wh + 262144;
    const int k0 = blockIdx.x * 32, n0 = blockIdx.y * 32;
    const bool f32 = (*flag) != 0;
    __shared__ float Tl[32][33];
    for (int it = 0; it < 4; ++it) {
        const int idx = it * 256 + threadIdx.x;
        const int lk = idx >> 5, ln = idx & 31;
        Tl[lk][ln] = f32 ? ldin<true>(W, (size_t)(k0 + lk) * 512 + n0 + ln)
                         : ldin<false>(W, (size_t)(k0 + lk) * 512 + n0 + ln);
    }
    __syncthreads();
    for (int it = 0; it < 4; ++it) {
        const int idx = it * 256 + threadIdx.x;
        const int ln = idx >> 5, lk = idx & 31;
        const float v = Tl[lk][ln];
        const bf16 h = f2b(v);
        Wh[(size_t)(n0 + ln) * 512 + k0 + lk] = h;
        Wl[(size_t)(n0 + ln) * 512 + k0 + lk] = f2b(v - b2f(h));
    }
}

// ---------------------------------------------------------------------------
// proj_mfma: C(fp32)[16384,512] = (xh+xl) @ (Wh+Wl) + bias. Split-bf16.
// 128x128 block, 4 waves (2x2 of 64x64), BK=32. XOR-swizzled LDS (stride 32).
// ---------------------------------------------------------------------------
__global__ __launch_bounds__(256) void proj_mfma(const bf16* __restrict__ xh,
                                                 const bf16* __restrict__ xl,
                                                 const bf16* __restrict__ WT,
                                                 const float* __restrict__ bias_f,
                                                 float* __restrict__ C0,
                                                 float* __restrict__ C1,
                                                 float* __restrict__ C2)
{
    const int z = blockIdx.z;
    const bf16* Bh = WT + (size_t)z * 524288;
    const bf16* Blo = Bh + 262144;
    float* C = z == 0 ? C0 : (z == 1 ? C1 : C2);
    const float* bias = bias_f + z * 512;

    const int m0 = blockIdx.x * 128, n0 = blockIdx.y * 128;
    const int tid = threadIdx.x, wv = tid >> 6, lane = tid & 63;
    const int wm = (wv >> 1) * 64, wn = (wv & 1) * 64;

    __shared__ __align__(16) bf16 Al[2][128][32];
    __shared__ __align__(16) bf16 Bl[2][128][32];

    f32x4 acc[4][4] = {};
    const int srow = tid >> 2, sq = tid & 3;
    const int mm = lane & 15, cc = lane >> 4;
    const int rpos = (cc ^ ((mm >> 1) & 3)) * 8;

    for (int kt = 0; kt < 512; kt += 32) {
        #pragma unroll
        for (int p = 0; p < 2; ++p) {
            const int r = p * 64 + srow;
            const int pos = (sq ^ ((r >> 1) & 3)) * 8;
            *(uint4*)&Al[0][r][pos] = *(const uint4*)&xh[(size_t)(m0 + r) * 512 + kt + sq * 8];
            *(uint4*)&Al[1][r][pos] = *(const uint4*)&xl[(size_t)(m0 + r) * 512 + kt + sq * 8];
            *(uint4*)&Bl[0][r][pos] = *(const uint4*)&Bh[(size_t)(n0 + r) * 512 + kt + sq * 8];
            *(uint4*)&Bl[1][r][pos] = *(const uint4*)&Blo[(size_t)(n0 + r) * 512 + kt + sq * 8];
        }
        __syncthreads();

        short8 a_h[4], a_l[4], b_h[4], b_l[4];
        #pragma unroll
        for (int i = 0; i < 4; ++i) {
            a_h[i] = *(const short8*)&Al[0][wm + i * 16 + mm][rpos];
            a_l[i] = *(const short8*)&Al[1][wm + i * 16 + mm][rpos];
            b_h[i] = *(const short8*)&Bl[0][wn + i * 16 + mm][rpos];
            b_l[i] = *(const short8*)&Bl[1][wn + i * 16 + mm][rpos];
        }
        #pragma unroll
        for (int i = 0; i < 4; ++i)
            #pragma unroll
            for (int j = 0; j < 4; ++j) {
                acc[i][j] = MFMA16(a_h[i], b_h[j], acc[i][j]);
                acc[i][j] = MFMA16(a_h[i], b_l[j], acc[i][j]);
                acc[i][j] = MFMA16(a_l[i], b_h[j], acc[i][j]);
            }
        __syncthreads();
    }

    const int nn2 = lane & 15, rq = (lane >> 4) * 4;
    #pragma unroll
    for (int i = 0; i < 4; ++i)
        #pragma unroll
        for (int j = 0; j < 4; ++j) {
            const int col = n0 + wn + j * 16 + nn2;
            const float bv = bias[col];
            #pragma unroll
            for (int r = 0; r < 4; ++r) {
                const int row = m0 + wm + i * 16 + rq + r;
                C[(size_t)row * 512 + col] = acc[i][j][r] + bv;
            }
        }
}

// ---------------------------------------------------------------------------
// out_mfma: out[16384,512] = Ct16(bf16) @ WoT + bias. Plain bf16, swizzled.
// ---------------------------------------------------------------------------
__global__ __launch_bounds__(256) void out_mfma(const bf16* __restrict__ A,
                                                const bf16* __restrict__ BhT,
                                                const float* __restrict__ bias,
                                                void* __restrict__ out,
                                                const int* __restrict__ flag)
{
    const int m0 = blockIdx.x * 128, n0 = blockIdx.y * 128;
    const int tid = threadIdx.x, wv = tid >> 6, lane = tid & 63;
    const int wm = (wv >> 1) * 64, wn = (wv & 1) * 64;

    __shared__ __align__(16) bf16 Al[128][32];
    __shared__ __align__(16) bf16 Bl[128][32];

    f32x4 acc[4][4] = {};
    const int srow = tid >> 2, sq = tid & 3;
    const int mm = lane & 15, cc = lane >> 4;
    const int rpos = (cc ^ ((mm >> 1) & 3)) * 8;

    for (int kt = 0; kt < 512; kt += 32) {
        #pragma unroll
        for (int p = 0; p < 2; ++p) {
            const int r = p * 64 + srow;
            const int pos = (sq ^ ((r >> 1) & 3)) * 8;
            *(uint4*)&Al[r][pos] = *(const uint4*)&A[(size_t)(m0 + r) * 512 + kt + sq * 8];
            *(uint4*)&Bl[r][pos] = *(const uint4*)&BhT[(size_t)(n0 + r) * 512 + kt + sq * 8];
        }
        __syncthreads();

        short8 af[4], bfr[4];
        #pragma unroll
        for (int i = 0; i < 4; ++i) {
            af[i]  = *(const short8*)&Al[wm + i * 16 + mm][rpos];
            bfr[i] = *(const short8*)&Bl[wn + i * 16 + mm][rpos];
        }
        #pragma unroll
        for (int i = 0; i < 4; ++i)
            #pragma unroll
            for (int j = 0; j < 4; ++j)
                acc[i][j] = MFMA16(af[i], bfr[j], acc[i][j]);
        __syncthreads();
    }

    const bool f32o = (*flag) != 0;
    const int nn2 = lane & 15, rq = (lane >> 4) * 4;
    #pragma unroll
    for (int i = 0; i < 4; ++i)
        #pragma unroll
        for (int j = 0; j < 4; ++j) {
            const int col = n0 + wn + j * 16 + nn2;
            const float bv = bias[col];
            #pragma unroll
            for (int r = 0; r < 4; ++r) {
                const int row = m0 + wm + i * 16 + rq + r;
                const float v = acc[i][j][r] + bv;
                if (f32o) ((float*)out)[(size_t)row * 512 + col] = v;
                else      ((bf16*)out)[(size_t)row * 512 + col] = f2b(v);
            }
        }
}

// ---------------------------------------------------------------------------
// rfft_cols: packed 2-real-columns-as-one-complex forward FFT (L=2048).
// ---------------------------------------------------------------------------
__global__ __launch_bounds__(256) void rfft_cols(const float* __restrict__ src,
                                                 float2* __restrict__ dst)
{
    const int b = blockIdx.y;
    const int d0 = blockIdx.x * 2;
    __shared__ __align__(16) float2 sh[2][2048];
    __shared__ __align__(16) float2 tw[1024];
    const int tid = threadIdx.x;

    for (int i = tid; i < 1024; i += 256) {
        float s, c;
        __sincosf(-6.283185307179586f * (float)i * (1.0f / 2048.0f), &s, &c);
        tw[i] = make_float2(c, s);
    }
    for (int l = tid; l < 2048; l += 256)
        sh[0][l] = make_float2(src[(size_t)(b * 2048 + l) * 512 + d0],
                               src[(size_t)(b * 2048 + l) * 512 + d0 + 1]);
    __syncthreads();

    int cur = 0, s = 1, ls = 0, tsh = 0;
    for (int nn = 2048; nn > 1; nn >>= 1) {
        const int m = nn >> 1;
        for (int t = tid; t < 1024; t += 256) {
            const int p = t >> ls;
            const int q = t & (s - 1);
            const float2 w  = tw[p << tsh];
            const float2 a  = sh[cur][q + s * p];
            const float2 bb = sh[cur][q + s * (p + m)];
            const float dx = a.x - bb.x, dy = a.y - bb.y;
            sh[cur ^ 1][q + s * 2 * p]       = make_float2(a.x + bb.x, a.y + bb.y);
            sh[cur ^ 1][q + s * (2 * p + 1)] = make_float2(dx * w.x - dy * w.y, dx * w.y + dy * w.x);
        }
        __syncthreads();
        cur ^= 1; s <<= 1; ++ls; ++tsh;
    }
    for (int f = tid; f < FF; f += 256) {
        const float2 Zf = sh[cur][f];
        const float2 Zc = sh[cur][(2048 - f) & 2047];
        const float2 X1 = make_float2(0.5f * (Zf.x + Zc.x), 0.5f * (Zf.y - Zc.y));
        const float wx = Zf.x - Zc.x, wy = Zf.y + Zc.y;
        const float2 X2 = make_float2(0.5f * wy, -0.5f * wx);
        dst[(size_t)(b * FF + f) * 512 + d0]     = X1;
        dst[(size_t)(b * FF + f) * 512 + d0 + 1] = X2;
    }
}

// ---------------------------------------------------------------------------
// irfft_cols: packed 2-column inverse; writes bf16 time-domain.
// ---------------------------------------------------------------------------
__global__ __launch_bounds__(256) void irfft_cols(const float2* __restrict__ Cf,
                                                  bf16* __restrict__ Ct16)
{
    const int b = blockIdx.y;
    const int d0 = blockIdx.x * 2;
    __shared__ __align__(16) float2 sh[2][2048];
    __shared__ __align__(16) float2 tw[1024];
    const int tid = threadIdx.x;

    for (int i = tid; i < 1024; i += 256) {
        float s, c;
        __sincosf(-6.283185307179586f * (float)i * (1.0f / 2048.0f), &s, &c);
        tw[i] = make_float2(c, s);
    }
    for (int f = tid; f < FF; f += 256) {
        float2 c1 = Cf[(size_t)(b * FF + f) * 512 + d0];
        float2 c2 = Cf[(size_t)(b * FF + f) * 512 + d0 + 1];
        if (f == 0 || f == 1024) { c1.y = 0.f; c2.y = 0.f; }
        sh[0][f] = make_float2(c1.x - c2.y, c1.y + c2.x);
        if (f >= 1 && f <= 1023)
            sh[0][2048 - f] = make_float2(c1.x + c2.y, -c1.y + c2.x);
    }
    __syncthreads();

    int cur = 0, s = 1, ls = 0, tsh = 0;
    for (int nn = 2048; nn > 1; nn >>= 1) {
        const int m = nn >> 1;
        for (int t = tid; t < 1024; t += 256) {
            const int p = t >> ls;
            const int q = t & (s - 1);
            const float2 wv = tw[p << tsh];
            const float2 w = make_float2(wv.x, -wv.y);
            const float2 a  = sh[cur][q + s * p];
            const float2 bb = sh[cur][q + s * (p + m)];
            const float dx = a.x - bb.x, dy = a.y - bb.y;
            sh[cur ^ 1][q + s * 2 * p]       = make_float2(a.x + bb.x, a.y + bb.y);
            sh[cur ^ 1][q + s * (2 * p + 1)] = make_float2(dx * w.x - dy * w.y, dx * w.y + dy * w.x);
        }
        __syncthreads();
        cur ^= 1; s <<= 1; ++ls; ++tsh;
    }
    for (int l = tid; l < 2048; l += 256) {
        const float2 z = sh[cur][l];
        Ct16[(size_t)(b * 2048 + l) * 512 + d0]     = f2b(z.x * (1.0f / 2048.0f));
        Ct16[(size_t)(b * 2048 + l) * 512 + d0 + 1] = f2b(z.y * (1.0f / 2048.0f));
    }
}

// ---------------------------------------------------------------------------
// split_qk: freq float2 -> 4 bf16 planes (re_hi | re_lo | im_hi | im_lo)
// ---------------------------------------------------------------------------
__global__ __launch_bounds__(256) void split_qk(const float2* __restrict__ src,
                                                bf16* __restrict__ dst)
{
    const size_t SP = (size_t)BB * FF * DD;
    const size_t i = (size_t)blockIdx.x * 256 + threadIdx.x;
    if (i >= SP) return;
    const float2 v = src[i];
    const bf16 h0 = f2b(v.x);
    const bf16 h1 = f2b(v.y);
    dst[i]          = h0;
    dst[i + SP]     = f2b(v.x - b2f(h0));
    dst[i + 2 * SP] = h1;
    dst[i + 3 * SP] = f2b(v.y - b2f(h1));
}

// ---------------------------------------------------------------------------
// att_mfma v2: att[b,f,g] = scale*|Q·K| (complex, no conj), split-bf16.
// Block 128f x 64g, 4 waves (2f x 2g), wave = 64f x 32g (4x2 subtiles).
// Sign-flip trick: ar = Qr·Kr + Qi·(-Ki) -> 2 accs/pair (not 4).
// XOR-swizzled LDS, stride 32, conflict-free. OOB rows read unguarded
// (lands in adjacent ws slots, harmless) and discarded at the C-write.
// ---------------------------------------------------------------------------
__global__ __launch_bounds__(256, 2) void att_mfma(const bf16* __restrict__ Asp,
                                                   const bf16* __restrict__ Bsp,
                                                   float* __restrict__ att)
{
    const size_t SP = (size_t)BB * FF * DD;
    const int b = blockIdx.z;
    const int g0 = blockIdx.x * 64;    // g fastest: A-band L2-resident
    const int f0 = blockIdx.y * 128;
    const int tid = threadIdx.x;
    const int wv = tid >> 6, lane = tid & 63;
    const int wvf = wv >> 1, wvg = wv & 1;

    __shared__ __align__(16) bf16 Al[4][128][32];   // 32 KB
    __shared__ __align__(16) bf16 Bl[4][64][32];    // 16 KB

    f32x4 accr[4][2] = {}; f32x4 acci[4][2] = {};

    const int srow = tid >> 2, sq = tid & 3;
    const int r16 = lane & 15, cc = lane >> 4;
    const int rpos = (cc ^ ((r16 >> 1) & 3)) * 8;
    const size_t abase = (size_t)(b * FF + f0) * 512;
    const size_t bbase = (size_t)(b * FF + g0) * 512;

    for (int kt = 0; kt < 512; kt += 32) {
        #pragma unroll
        for (int p = 0; p < 2; ++p) {
            const int row = p * 64 + srow;
            const int pos = (sq ^ ((row >> 1) & 3)) * 8;
            #pragma unroll
            for (int pl = 0; pl < 4; ++pl)
                *(uint4*)&Al[pl][row][pos] =
                    *(const uint4*)&Asp[(size_t)pl * SP + abase + (size_t)row * 512 + kt + sq * 8];
        }
        {
            const int pos = (sq ^ ((srow >> 1) & 3)) * 8;
            #pragma unroll
            for (int pl = 0; pl < 4; ++pl)
                *(uint4*)&Bl[pl][srow][pos] =
                    *(const uint4*)&Bsp[(size_t)pl * SP + bbase + (size_t)srow * 512 + kt + sq * 8];
        }
        __syncthreads();

        short8 aA[4][4], bB[2][4], nb[2][2];
        #pragma unroll
        for (int i = 0; i < 4; ++i) {
            const int row = wvf * 64 + i * 16 + r16;
            #pragma unroll
            for (int pl = 0; pl < 4; ++pl)
                aA[i][pl] = *(const short8*)&Al[pl][row][rpos];
        }
        #pragma unroll
        for (int j = 0; j < 2; ++j) {
            const int row = wvg * 32 + j * 16 + r16;
            #pragma unroll
            for (int pl = 0; pl < 4; ++pl)
                bB[j][pl] = *(const short8*)&Bl[pl][row][rpos];
            nb[j][0] = neg8(bB[j][2]);
            nb[j][1] = neg8(bB[j][3]);
        }
        // planes: 0=re_hi 1=re_lo 2=im_hi 3=im_lo
        #pragma unroll
        for (int i = 0; i < 4; ++i)
            #pragma unroll
            for (int j = 0; j < 2; ++j) {
                accr[i][j] = MFMA16(aA[i][0], bB[j][0], accr[i][j]);
                accr[i][j] = MFMA16(aA[i][0], bB[j][1], accr[i][j]);
                accr[i][j] = MFMA16(aA[i][1], bB[j][0], accr[i][j]);
                accr[i][j] = MFMA16(aA[i][2], nb[j][0], accr[i][j]);
                accr[i][j] = MFMA16(aA[i][2], nb[j][1], accr[i][j]);
                accr[i][j] = MFMA16(aA[i][3], nb[j][0], accr[i][j]);
                acci[i][j] = MFMA16(aA[i][0], bB[j][2], acci[i][j]);
                acci[i][j] = MFMA16(aA[i][0], bB[j][3], acci[i][j]);
                acci[i][j] = MFMA16(aA[i][1], bB[j][2], acci[i][j]);
                acci[i][j] = MFMA16(aA[i][2], bB[j][0], acci[i][j]);
                acci[i][j] = MFMA16(aA[i][2], bB[j][1], acci[i][j]);
                acci[i][j] = MFMA16(aA[i][3], bB[j][0], acci[i][j]);
            }
        __syncthreads();
    }

    const int rq = (lane >> 4) * 4;
    #pragma unroll
    for (int i = 0; i < 4; ++i)
        #pragma unroll
        for (int j = 0; j < 2; ++j)
            #pragma unroll
            for (int r = 0; r < 4; ++r) {
                const int f = f0 + wvf * 64 + i * 16 + rq + r;
                const int g = g0 + wvg * 32 + j * 16 + r16;
                if (f < FF && g < FF) {
                    const float ar = accr[i][j][r];
                    const float ai = acci[i][j][r];
                    att[((size_t)(b * FF + f)) * FF + g] = ATT_SCALE * sqrtf(ar * ar + ai * ai);
                }
            }
}

// ---------------------------------------------------------------------------
// softmax over g per (b,f) row; fp32 in place + bf16 copy padded to GP.
// ---------------------------------------------------------------------------
__global__ __launch_bounds__(256) void softmax_rows(float* __restrict__ att,
                                                    bf16* __restrict__ att16)
{
    const int row = blockIdx.x;
    float* p = att + (size_t)row * FF;
    bf16* q = att16 + (size_t)row * GP;
    const int tid = threadIdx.x;
    const int lane = tid & 63, wid = tid >> 6;
    __shared__ float red[4];

    float m = -1e30f;
    for (int i = tid; i < FF; i += 256) m = fmaxf(m, p[i]);
    #pragma unroll
    for (int o = 32; o; o >>= 1) m = fmaxf(m, __shfl_down(m, o));
    if (lane == 0) red[wid] = m;
    __syncthreads();
    m = fmaxf(fmaxf(red[0], red[1]), fmaxf(red[2], red[3]));
    __syncthreads();

    float s = 0.f;
    for (int i = tid; i < FF; i += 256) { const float e = expf(p[i] - m); p[i] = e; s += e; }
    #pragma unroll
    for (int o = 32; o; o >>= 1) s += __shfl_down(s, o);
    if (lane == 0) red[wid] = s;
    __syncthreads();
    s = red[0] + red[1] + red[2] + red[3];
    const float inv = 1.f / s;
    for (int i = tid; i < GP; i += 256) {
        if (i < FF) {
            const float v = p[i] * inv;
            p[i] = v;
            q[i] = f2b(v);
        } else {
            q[i] = f2b(0.f);
        }
    }
}

// ---------------------------------------------------------------------------
// transpose V: Vf[b,g,d] float2 -> Vct[b,n,g] bf16 (n<512 re, else im).
// ---------------------------------------------------------------------------
__global__ __launch_bounds__(256) void transpose_v(const float2* __restrict__ Vf,
                                                   bf16* __restrict__ Vct)
{
    const int b = blockIdx.z;
    const int d0 = blockIdx.x * 32;
    const int g0 = blockIdx.y * 32;
    __shared__ float2 Tl[32][33];
    const int tid = threadIdx.x;

    for (int k = 0; k < 4; ++k) {
        const int idx = k * 256 + tid;
        const int lg = idx >> 5, ld = idx & 31;
        const int g = g0 + lg;
        Tl[lg][ld] = (g < FF) ? Vf[((size_t)(b * FF + g)) * 512 + d0 + ld]
                              : make_float2(0.f, 0.f);
    }
    __syncthreads();
    for (int k = 0; k < 4; ++k) {
        const int idx = k * 256 + tid;
        const int ld = idx >> 5, lg = idx & 31;
        const float2 v = Tl[lg][ld];
        Vct[((size_t)(b * 1024 + d0 + ld)) * GP + g0 + lg]       = f2b(v.x);
        Vct[((size_t)(b * 1024 + 512 + d0 + ld)) * GP + g0 + lg] = f2b(v.y);
    }
}

// ---------------------------------------------------------------------------
// ctx_mfma: Cf[b,f,d] = sum_g attn * Vf (bf16 MFMA, K=GP), swizzled LDS.
// ---------------------------------------------------------------------------
__global__ __launch_bounds__(256) void ctx_mfma(const bf16* __restrict__ att16,
                                                const bf16* __restrict__ Vct,
                                                float* __restrict__ Cf)
{
    const int b = blockIdx.z;
    const int f0 = blockIdx.x * 64, n0 = blockIdx.y * 64;
    const int tid = threadIdx.x;
    const int wv = tid >> 6, lane = tid & 63;
    const int wf = (wv >> 1) * 32, wn = (wv & 1) * 32;

    __shared__ __align__(16) bf16 Al[64][32];
    __shared__ __align__(16) bf16 Bl[64][32];

    f32x4 acc[2][2] = {};
    const int srow = tid >> 2, sq = tid & 3;
    const int m = lane & 15, cc = lane >> 4;
    const int rpos = (cc ^ ((m >> 1) & 3)) * 8;
    const int spos = (sq ^ ((srow >> 1) & 3)) * 8;

    for (int kt = 0; kt < GP; kt += 32) {
        uint4 av = make_uint4(0, 0, 0, 0);
        if (f0 + srow < FF)
            av = *(const uint4*)&att16[((size_t)(b * FF + f0 + srow)) * GP + kt + sq * 8];
        *(uint4*)&Al[srow][spos] = av;
        *(uint4*)&Bl[srow][spos] =
            *(const uint4*)&Vct[((size_t)(b * 1024 + n0 + srow)) * GP + kt + sq * 8];
        __syncthreads();

        short8 af[2], bfr[2];
        #pragma unroll
        for (int s = 0; s < 2; ++s) {
            af[s]  = *(const short8*)&Al[wf + s * 16 + m][rpos];
            bfr[s] = *(const short8*)&Bl[wn + s * 16 + m][rpos];
        }
        #pragma unroll
        for (int i = 0; i < 2; ++i)
            #pragma unroll
            for (int j = 0; j < 2; ++j)
                acc[i][j] = MFMA16(af[i], bfr[j], acc[i][j]);
        __syncthreads();
    }

    const int nn = lane & 15, rq = (lane >> 4) * 4;
    #pragma unroll
    for (int i = 0; i < 2; ++i)
        #pragma unroll
        for (int j = 0; j < 2; ++j)
            #pragma unroll
            for (int r = 0; r < 4; ++r) {
                const int f = f0 + wf + i * 16 + rq + r;
                const int n = n0 + wn + j * 16 + nn;
                if (f < FF) {
                    const int d = n & 511, im = n >> 9;
                    Cf[(((size_t)(b * FF + f)) * 512 + d) * 2 + im] = acc[i][j][r];
                }
            }
}

// ---------------------------------------------------------------------------
// launch — 4x33.65MB slots + 4MB weight region + bias + flag (~138.8 MB)
// ---------------------------------------------------------------------------
extern "C" void kernel_launch(void* const* d_in, const int* in_sizes, int n_in,
                              void* d_out, int out_size, void* d_ws, size_t ws_size,
                              hipStream_t stream)
{
    const void* x  = d_in[0];
    const void* Wq = d_in[1]; const void* bq = d_in[2];
    const void* Wk = d_in[3]; const void* bk = d_in[4];
    const void* Wv = d_in[5]; const void* bv = d_in[6];
    const void* Wo = d_in[7]; const void* bo = d_in[8];

    const size_t SLOT = 33652736;
    char* ws = (char*)d_ws;
    char* s0 = ws;               char* s1 = ws + SLOT;
    char* s2 = ws + 2 * SLOT;    char* s3 = ws + 3 * SLOT;
    char* wreg = ws + 4 * SLOT;
    bf16*  WT     = (bf16*)wreg;
    float* bias_f = (float*)(wreg + 4194304);
    int*   flag   = (int*)(wreg + 4194304 + 8192);

    bf16*   xh   = (bf16*)s3;
    bf16*   xl   = (bf16*)(s3 + 16777216);
    float*  Qt   = (float*)s0;  float* Kt = (float*)s1;  float* Vt = (float*)s2;
    float2* Qf   = (float2*)s3;
    bf16*   Asp  = (bf16*)s0;
    float2* Kf   = (float2*)s3;
    bf16*   Bsp  = (bf16*)s1;
    float2* Vf   = (float2*)s3;
    bf16*   Vct  = (bf16*)s2;
    float*  attn = (float*)s3;
    bf16*   att16= (bf16*)s0;
    float2* Cf   = (float2*)s1;
    bf16*   Ct16 = (bf16*)s2;

    const int SPLITQ_BLOCKS = (int)(((size_t)BB * FF * DD + 255) / 256);
    const int SPLITX_BLOCKS = (int)(((size_t)BB * LL * DD + 255) / 256);

    detect_dtype<<<1, 256, 0, stream>>>((const unsigned short*)x, flag);
    prep_bias<<<8, 256, 0, stream>>>(bq, bk, bv, bo, bias_f, flag);
    split_x<<<SPLITX_BLOCKS, 256, 0, stream>>>(x, xh, xl, flag);
    split_w_t<<<dim3(16, 16, 4), 256, 0, stream>>>(Wq, Wk, Wv, Wo, WT, flag);
    proj_mfma<<<dim3(128, 4, 3), 256, 0, stream>>>(xh, xl, WT, bias_f, Qt, Kt, Vt);
    rfft_cols<<<dim3(256, 8), 256, 0, stream>>>(Qt, Qf);
    split_qk<<<SPLITQ_BLOCKS, 256, 0, stream>>>(Qf, Asp);
    rfft_cols<<<dim3(256, 8), 256, 0, stream>>>(Kt, Kf);
    split_qk<<<SPLITQ_BLOCKS, 256, 0, stream>>>(Kf, Bsp);
    rfft_cols<<<dim3(256, 8), 256, 0, stream>>>(Vt, Vf);
    transpose_v<<<dim3(16, 33, 8), 256, 0, stream>>>(Vf, Vct);
    att_mfma<<<dim3(17, 9, 8), 256, 0, stream>>>(Asp, Bsp, attn);
    softmax_rows<<<dim3(BB * FF), 256, 0, stream>>>(attn, att16);
    ctx_mfma<<<dim3(17, 16, 8), 256, 0, stream>>>(att16, Vct, (float*)Cf);
    irfft_cols<<<dim3(256, 8), 256, 0, stream>>>(Cf, Ct16);
    out_mfma<<<dim3(128, 4), 256, 0, stream>>>(Ct16, WT + 3 * 524288, bias_f + 3 * 512,
                                               d_out, flag);
}